// Round 11
// baseline (446.492 us; speedup 1.0000x reference)
//
#include <hip/hip_runtime.h>
#include <hip/hip_bf16.h>

#define T 2048
#define NR 1024
#define TOPK 40

static __device__ __forceinline__ float bnscale() { return 0.9999950000374997f; } // 1/sqrt(1+1e-5)

// ---------------------------------------------------------------- kernel 1: bn -> conv q,k (k=3) + v (k=1)
__global__ __launch_bounds__(256) void k_qkv(
    const float* __restrict__ x, const float* __restrict__ n1_g, const float* __restrict__ n1_b,
    const float* __restrict__ wq, const float* __restrict__ bnq_g, const float* __restrict__ bnq_b,
    const float* __restrict__ wk, const float* __restrict__ bnk_g, const float* __restrict__ bnk_b,
    const float* __restrict__ wv,
    float* __restrict__ q_t, float* __restrict__ k_t, float* __restrict__ v_t,
    float* __restrict__ q_rc, float* __restrict__ k_rc)
{
  const int b = blockIdx.y;
  const int tile = blockIdx.x >> 2;
  const int oc0 = (blockIdx.x & 3) * 16;
  const int t0 = tile * 64;
  const int r0 = tile * 32;
  const int tid = threadIdx.x;
  const float INVS = bnscale();

  __shared__ float xn[64][67];   // [c][tt], tt covers t0-1 .. t0+64
  __shared__ float ot[16][67];   // [oc_local][t_local]

  for (int i = tid; i < 64 * 66; i += 256) {
    int c = i / 66, tt = i - c * 66;
    int t = t0 + tt - 1;
    float v = (t >= 0 && t < T) ? x[(size_t)(b * 64 + c) * T + t] : 0.f;
    xn[c][tt] = v * (n1_g[c] * INVS) + n1_b[c];
  }
  __syncthreads();

  const int w = tid >> 6, lane = tid & 63;
  const int ob = oc0 + __builtin_amdgcn_readfirstlane(w) * 4;  // wave-uniform -> SGPR weight loads

  float accq[4], acck[4], accv[4];
#pragma unroll
  for (int j = 0; j < 4; ++j) { accq[j] = 0.f; acck[j] = 0.f; accv[j] = 0.f; }

#pragma unroll 1
  for (int c0 = 0; c0 < 64; c0 += 4) {
    float xr[4][3];
#pragma unroll
    for (int cc = 0; cc < 4; ++cc) {
      xr[cc][0] = xn[c0 + cc][lane];
      xr[cc][1] = xn[c0 + cc][lane + 1];
      xr[cc][2] = xn[c0 + cc][lane + 2];
    }
#pragma unroll
    for (int o4 = 0; o4 < 4; ++o4) {
      int o = ob + o4;
      const float* wqo = wq + o * 192 + c0 * 3;
      const float* wko = wk + o * 192 + c0 * 3;
      const float* wvo = wv + o * 64 + c0;
      float aq = accq[o4], ak = acck[o4], av = accv[o4];
#pragma unroll
      for (int cc = 0; cc < 4; ++cc) {
        aq += xr[cc][0] * wqo[cc * 3 + 0] + xr[cc][1] * wqo[cc * 3 + 1] + xr[cc][2] * wqo[cc * 3 + 2];
        ak += xr[cc][0] * wko[cc * 3 + 0] + xr[cc][1] * wko[cc * 3 + 1] + xr[cc][2] * wko[cc * 3 + 2];
        av += xr[cc][1] * wvo[cc];
      }
      accq[o4] = aq; acck[o4] = ak; accv[o4] = av;
    }
  }

  // ---- Q: bn, transpose-store slice, region means ----
#pragma unroll
  for (int o4 = 0; o4 < 4; ++o4) {
    int o = ob + o4;
    ot[o - oc0][lane] = accq[o4] * (bnq_g[o] * INVS) + bnq_b[o];
  }
  __syncthreads();
  for (int i = tid; i < 1024; i += 256) {
    int cl = i & 15, tt = i >> 4;
    q_t[((size_t)(b * T + t0 + tt)) * 64 + oc0 + cl] = ot[cl][tt];
  }
  for (int i = tid; i < 512; i += 256) {
    int rr = i & 31, cl = i >> 5;
    q_rc[((size_t)(b * 64 + oc0 + cl)) * NR + r0 + rr] = 0.5f * (ot[cl][2 * rr] + ot[cl][2 * rr + 1]);
  }
  __syncthreads();

  // ---- K ----
#pragma unroll
  for (int o4 = 0; o4 < 4; ++o4) {
    int o = ob + o4;
    ot[o - oc0][lane] = acck[o4] * (bnk_g[o] * INVS) + bnk_b[o];
  }
  __syncthreads();
  for (int i = tid; i < 1024; i += 256) {
    int cl = i & 15, tt = i >> 4;
    k_t[((size_t)(b * T + t0 + tt)) * 64 + oc0 + cl] = ot[cl][tt];
  }
  for (int i = tid; i < 512; i += 256) {
    int rr = i & 31, cl = i >> 5;
    k_rc[((size_t)(b * 64 + oc0 + cl)) * NR + r0 + rr] = 0.5f * (ot[cl][2 * rr] + ot[cl][2 * rr + 1]);
  }
  __syncthreads();

  // ---- V ----
#pragma unroll
  for (int o4 = 0; o4 < 4; ++o4) {
    ot[ob + o4 - oc0][lane] = accv[o4];
  }
  __syncthreads();
  for (int i = tid; i < 1024; i += 256) {
    int cl = i & 15, tt = i >> 4;
    v_t[((size_t)(b * T + t0 + tt)) * 64 + oc0 + cl] = ot[cl][tt];
  }
}

// ---------------------------------------------------------------- kernel 2: region scores + top-40
// v8: transposed wave->work mapping. Wave w owns ALL 16 rows x column quarter [256w,256w+256):
// per-wave B loads 256 -> 64 float4 (per-CU traffic 4 MB -> 1 MB, the diagnosed latency wall),
// register-only double-buffered prefetch (kA/kB ping-pong, NO barriers, no LDS round-trip --
// v7's barrier-coupled LDS staging spilled and serialized). Quickselect per row runs on 4
// regs x 16 rows (same aggregate ballots as v6); each wave emits its quarter's exactly-40 to
// LDS list[16][160]; one barrier; rank-merge (union of quarter-top-40s contains global top-40,
// rank within union = global rank; unique packed values -> identical selection set to v6).
__global__ __launch_bounds__(256) void k_scores(
    const float* __restrict__ q_rc, const float* __restrict__ k_rc, int* __restrict__ sel)
{
  const int ib = blockIdx.x;
  const int xcd = ib & 7;
  const int slot = ib >> 3;             // 0..127
  const int b = xcd * 2 + (slot >> 6);  // 2 batches per XCD
  const int r0 = (slot & 63) * 16;
  const int tid = threadIdx.x;
  const int w = tid >> 6, lane = tid & 63;

  __shared__ float qsT[16][68];        // [row][c]
  __shared__ unsigned list[16][160];   // per-row: 4 quarters x 40 candidates

  for (int i = tid; i < 1024; i += 256) {
    int rr = i & 15, c = i >> 4;
    qsT[rr][c] = q_rc[((size_t)(b * 64 + c)) * NR + r0 + rr];
  }
  __syncthreads();

  // ---- GEMM: wave w computes rows 0..15 x cols 256w + 4*lane + s ----
  const float4* kp4 = (const float4*)(k_rc + ((size_t)b * 64) * NR);
  const int coff = w * 64 + lane;      // float4 column offset of this lane's quarter slot

  float4 acc[16];
#pragma unroll
  for (int r = 0; r < 16; ++r) acc[r] = make_float4(0.f, 0.f, 0.f, 0.f);

  float4 kA[4], kB[4];
#pragma unroll
  for (int u = 0; u < 4; ++u) kA[u] = kp4[(size_t)u * 256 + coff];

#pragma unroll 1
  for (int ch = 0; ch < 16; ch += 2) {
    // prefetch chunk ch+1 into kB (registers only)
#pragma unroll
    for (int u = 0; u < 4; ++u) kB[u] = kp4[(size_t)((ch + 1) * 4 + u) * 256 + coff];
    // compute chunk ch from kA
    {
      const int c0 = ch * 4;
#pragma unroll
      for (int r = 0; r < 16; ++r) {
        float4 qv = *(const float4*)&qsT[r][c0];
        acc[r].x += qv.x * kA[0].x + qv.y * kA[1].x + qv.z * kA[2].x + qv.w * kA[3].x;
        acc[r].y += qv.x * kA[0].y + qv.y * kA[1].y + qv.z * kA[2].y + qv.w * kA[3].y;
        acc[r].z += qv.x * kA[0].z + qv.y * kA[1].z + qv.z * kA[2].z + qv.w * kA[3].z;
        acc[r].w += qv.x * kA[0].w + qv.y * kA[1].w + qv.z * kA[2].w + qv.w * kA[3].w;
      }
    }
    // prefetch chunk ch+2 into kA
    if (ch + 2 < 16) {
#pragma unroll
      for (int u = 0; u < 4; ++u) kA[u] = kp4[(size_t)((ch + 2) * 4 + u) * 256 + coff];
    }
    // compute chunk ch+1 from kB
    {
      const int c0 = (ch + 1) * 4;
#pragma unroll
      for (int r = 0; r < 16; ++r) {
        float4 qv = *(const float4*)&qsT[r][c0];
        acc[r].x += qv.x * kB[0].x + qv.y * kB[1].x + qv.z * kB[2].x + qv.w * kB[3].x;
        acc[r].y += qv.x * kB[0].y + qv.y * kB[1].y + qv.z * kB[2].y + qv.w * kB[3].y;
        acc[r].z += qv.x * kB[0].z + qv.y * kB[1].z + qv.z * kB[2].z + qv.w * kB[3].z;
        acc[r].w += qv.x * kB[0].w + qv.y * kB[1].w + qv.z * kB[2].w + qv.w * kB[3].w;
      }
    }
  }

  // ---- pack to sortable u32: hi 22 = score (sign-flip), lo 10 = 1023-idx (unique) ----
  unsigned pk[16][4];
#pragma unroll
  for (int r = 0; r < 16; ++r) {
    const float* av = &acc[r].x;
#pragma unroll
    for (int s = 0; s < 4; ++s) {
      unsigned u = __float_as_uint(av[s]);
      u ^= (unsigned)((int)u >> 31) | 0x80000000u;
      int idx = 256 * w + 4 * lane + s;
      pk[r][s] = (u & 0xFFFFFC00u) | (unsigned)(1023 - idx);
    }
  }

  // ---- per-quarter ballot-quickselect: exactly-40 threshold per row over this wave's 256 ----
  unsigned p[16];
#pragma unroll
  for (int r = 0; r < 16; ++r) p[r] = 0u;
  unsigned doneMask = 0;
#pragma unroll 1
  for (int bit = 31; bit >= 0; --bit) {
#pragma unroll
    for (int r = 0; r < 16; ++r) {
      if (doneMask & (1u << r)) continue;          // wave-uniform
      unsigned X = p[r] | (1u << bit);
      int c = 0;
#pragma unroll
      for (int j = 0; j < 4; ++j)
        c += __popcll(__ballot(pk[r][j] >= X));
      if (c >= TOPK) p[r] = X;
      if (c == TOPK) doneMask |= (1u << r);
    }
    if (doneMask == 0xFFFFu) break;
  }
  // invariant: count(v >= p[r]) == 40 after full descent (unique values)

  // ---- emit each quarter's 40 winners to LDS list[r][w*40 + rank-in-quarter] ----
#pragma unroll
  for (int r = 0; r < 16; ++r) {
    const unsigned X = p[r];
    int base = 0;
#pragma unroll
    for (int j = 0; j < 4; ++j) {
      bool win = pk[r][j] >= X;
      unsigned long long m = __ballot(win);
      int before = __builtin_amdgcn_mbcnt_hi((unsigned)(m >> 32),
                   __builtin_amdgcn_mbcnt_lo((unsigned)m, 0));
      if (win) list[r][w * 40 + base + before] = pk[r][j];
      base += __popcll(m);
    }
  }
  __syncthreads();

  // ---- rank-merge: wave w handles rows 4w..4w+3; lane covers candidates lane, +64, +128 ----
#pragma unroll
  for (int rr = 0; rr < 4; ++rr) {
    const int r = w * 4 + rr;
    unsigned v0 = list[r][lane];
    unsigned v1 = list[r][lane + 64];
    unsigned v2 = (lane < 32) ? list[r][lane + 128] : 0u;
    int g0 = 0, g1 = 0, g2 = 0;
#pragma unroll 4
    for (int i = 0; i < 160; ++i) {
      unsigned u = list[r][i];
      g0 += (u > v0) ? 1 : 0;
      g1 += (u > v1) ? 1 : 0;
      g2 += (u > v2) ? 1 : 0;
    }
    int* srow = sel + ((size_t)(b * NR + r0 + r)) * TOPK;
    if (g0 < TOPK) srow[g0] = 1023 - (int)(v0 & 1023u);
    if (g1 < TOPK) srow[g1] = 1023 - (int)(v1 & 1023u);
    if (lane < 32 && g2 < TOPK) srow[g2] = 1023 - (int)(v2 & 1023u);
  }
}

// ---------------------------------------------------------------- kernel 3: gathered attention + lepe depthwise + bias
// v2: + XCD-locality swizzle (grid 1D 16384; each XCD owns 2 batches -> gathered K/V working
// set ~2 MB fits per-XCD L2).
__global__ __launch_bounds__(256) void k_attn(
    const float* __restrict__ q_t, const float* __restrict__ k_t, const float* __restrict__ v_t,
    const int* __restrict__ sel, const float* __restrict__ lepe_w, const float* __restrict__ lepe_b,
    float* __restrict__ o_t)
{
  const int ib = blockIdx.x;
  const int xcd = ib & 7;
  const int slot = ib >> 3;               // 0..2047
  const int b = xcd * 2 + (slot >> 10);   // 2 batches per XCD
  const int r = slot & 1023;
  const int tid = threadIdx.x;

  __shared__ __align__(16) float kg[80][68];   // gathered K, 21.76 KB, rows 16B-aligned
  __shared__ __align__(16) float qb[2][64];
  __shared__ int   toff[80];                   // byte offset of gathered row within (b) plane
  __shared__ __align__(16) float lg[4][2][84]; // probs per head
  __shared__ float vl[4][64];                  // v rows 2r-1..2r+2 for lepe

  // part[half][sq][c] aliases kg (dead after QK^T)
  float (*part)[2][64] = (float (*)[2][64])&kg[0][0];

  if (tid < 40) {
    int s = sel[((size_t)(b * NR + r)) * TOPK + tid];
    toff[2 * tid]     = s * 512;        // row 2s   * 64 floats * 4 B
    toff[2 * tid + 1] = s * 512 + 256;  // row 2s+1
  }
  if (tid >= 128 && tid < 256) {
    int i = tid - 128;
    int s = i >> 6, c = i & 63;
    qb[s][c] = q_t[((size_t)(b * T + r * 2 + s)) * 64 + c];
  }
  {
    int idx = tid >> 6, c = tid & 63;
    int t = 2 * r - 1 + idx;
    vl[idx][c] = (t >= 0 && t < T) ? v_t[((size_t)(b * T + t)) * 64 + c] : 0.f;
  }
  __syncthreads();

  // ---- stage gathered K with float4 (5 iters/thread) ----
  {
    const char* kbase = (const char*)(k_t + (size_t)b * T * 64);
    for (int i = tid; i < 80 * 16; i += 256) {
      int row = i >> 4, c4 = i & 15;
      float4 kv = *(const float4*)(kbase + toff[row] + c4 * 16);
      *(float4*)&kg[row][c4 * 4] = kv;
    }
  }
  __syncthreads();

  const int h = tid >> 6, lane = tid & 63;

  // ---- QK^T: Q in registers, each gathered K row read once as 4 x b128, both sq per col ----
  {
    float4 q0[4], q1[4];
#pragma unroll
    for (int j = 0; j < 4; ++j) {
      q0[j] = *(const float4*)&qb[0][h * 16 + j * 4];
      q1[j] = *(const float4*)&qb[1][h * 16 + j * 4];
    }
    for (int col = lane; col < 80; col += 64) {
      float a0 = 0.f, a1 = 0.f;
#pragma unroll
      for (int j = 0; j < 4; ++j) {
        float4 kv = *(const float4*)&kg[col][h * 16 + j * 4];
        a0 += q0[j].x * kv.x + q0[j].y * kv.y + q0[j].z * kv.z + q0[j].w * kv.w;
        a1 += q1[j].x * kv.x + q1[j].y * kv.y + q1[j].z * kv.z + q1[j].w * kv.w;
      }
      lg[h][0][col] = a0 * 0.125f;  // 64^-0.5
      lg[h][1][col] = a1 * 0.125f;
    }
  }

  // ---- softmax (wave-local: lg[h] written and read by wave h only) ----
  for (int sq = 0; sq < 2; ++sq) {
    float a = lg[h][sq][lane];
    float bb = (lane < 16) ? lg[h][sq][64 + lane] : -INFINITY;
    float m = fmaxf(a, bb);
    for (int mm = 32; mm >= 1; mm >>= 1) m = fmaxf(m, __shfl_xor(m, mm));
    float ea = expf(a - m);
    float eb = (lane < 16) ? expf(bb - m) : 0.f;
    float ssum = ea + eb;
    for (int mm = 32; mm >= 1; mm >>= 1) ssum += __shfl_xor(ssum, mm);
    float inv = 1.f / ssum;
    lg[h][sq][lane] = ea * inv;
    if (lane < 16) lg[h][sq][64 + lane] = eb * inv;
  }
  __syncthreads();   // lg complete across heads; kg now dead -> part may reuse it

  // ---- PV: thread = (half, sq, c); p as float4, V rows coalesced from global (L2-hit) ----
  {
    const int c = tid & 63, j = tid >> 6;
    const int sq = j & 1, half = j >> 1;
    const int hh = c >> 4;
    const char* vbase = (const char*)(v_t + (size_t)b * T * 64) + c * 4;
    float acc = 0.f;
#pragma unroll 2
    for (int ch = 0; ch < 10; ++ch) {
      int col0 = half * 40 + ch * 4;
      float4 p = *(const float4*)&lg[hh][sq][col0];
      float v0 = *(const float*)(vbase + toff[col0 + 0]);
      float v1 = *(const float*)(vbase + toff[col0 + 1]);
      float v2 = *(const float*)(vbase + toff[col0 + 2]);
      float v3 = *(const float*)(vbase + toff[col0 + 3]);
      acc += p.x * v0 + p.y * v1 + p.z * v2 + p.w * v3;
    }
    part[half][sq][c] = acc;
  }
  __syncthreads();

  if (tid < 128) {
    int sq = tid >> 6, c = tid & 63;
    float o = part[0][sq][c] + part[1][sq][c];
    float lep = lepe_b[c];
#pragma unroll
    for (int kk = 0; kk < 3; ++kk) lep += lepe_w[c * 3 + kk] * vl[sq + kk][c];
    o_t[((size_t)(b * T + 2 * r + sq)) * 64 + c] = o + lep;
  }
}

// ---------------------------------------------------------------- kernel 4: out conv + residual + bn2 + fc1 + relu -> h_c (c-major)
__global__ __launch_bounds__(256) void k_mix(
    const float* __restrict__ x, const float* __restrict__ o_t,
    const float* __restrict__ out_w, const float* __restrict__ out_b,
    const float* __restrict__ n2_g, const float* __restrict__ n2_b,
    const float* __restrict__ fc1_w, const float* __restrict__ bn1_g, const float* __restrict__ bn1_b,
    float* __restrict__ xres, float* __restrict__ h_c)
{
  const int b = blockIdx.y;
  const int t0 = blockIdx.x * 16;
  const int tid = threadIdx.x;
  const float INVS = bnscale();

  __shared__ float ol[16][65];
  __shared__ float yn[16][65];
  __shared__ float xl[16][65];
  __shared__ float wo[64][65];    // out_w transposed: wo[cc][c]
  __shared__ float w1[128][65];   // fc1_w natural [cc][c]
  __shared__ float res2[128][17];

  for (int i = tid; i < 1024; i += 256) {
    int tt = i >> 6, c = i & 63;
    ol[tt][c] = o_t[((size_t)(b * T + t0 + tt)) * 64 + c];
  }
  for (int i = tid; i < 1024; i += 256) {
    int c = i >> 4, tt = i & 15;
    xl[tt][c] = x[(size_t)(b * 64 + c) * T + t0 + tt];
  }
  for (int i = tid; i < 4096; i += 256) {
    int c = i >> 6, cc = i & 63;
    wo[cc][c] = out_w[i];
  }
  for (int i = tid; i < 8192; i += 256) {
    int cc = i >> 6, c = i & 63;
    w1[cc][c] = fc1_w[i];
  }
  __syncthreads();

  // out conv: thread = (c, 4 tt's)
  {
    const int c = tid & 63, grp = tid >> 6;
    float a0 = out_b[c], a1 = a0, a2 = a0, a3 = a0;
    for (int cc = 0; cc < 64; ++cc) {
      float wv = wo[cc][c];
      a0 += wv * ol[grp * 4 + 0][cc];
      a1 += wv * ol[grp * 4 + 1][cc];
      a2 += wv * ol[grp * 4 + 2][cc];
      a3 += wv * ol[grp * 4 + 3][cc];
    }
    float g2 = n2_g[c] * INVS, b2 = n2_b[c];
    float av[4] = {a0, a1, a2, a3};
#pragma unroll
    for (int j = 0; j < 4; ++j) {
      int tt = grp * 4 + j;
      float xr = xl[tt][c] + av[j];
      xres[((size_t)(b * T + t0 + tt)) * 64 + c] = xr;
      yn[tt][c] = xr * g2 + b2;
    }
  }
  __syncthreads();

  // fc1 + bn1 + relu: thread = (cc, 8 tt's)
  {
    const int cc = tid & 127, half = tid >> 7;
    float acc[8];
#pragma unroll
    for (int j = 0; j < 8; ++j) acc[j] = 0.f;
    for (int c = 0; c < 64; ++c) {
      float wv = w1[cc][c];
#pragma unroll
      for (int j = 0; j < 8; ++j) acc[j] += wv * yn[half * 8 + j][c];
    }
    float g1 = bn1_g[cc] * INVS, b1 = bn1_b[cc];
#pragma unroll
    for (int j = 0; j < 8; ++j)
      res2[cc][half * 8 + j] = fmaxf(acc[j] * g1 + b1, 0.f);
  }
  __syncthreads();

  for (int i = tid; i < 2048; i += 256) {
    int tt = i & 15, cc = i >> 4;
    h_c[((size_t)(b * 128 + cc)) * T + t0 + tt] = res2[cc][tt];
  }
}

// ---------------------------------------------------------------- kernel 5: FFT radix-4 (5 stages + radix-2) -> diag filter + relu -> mirrored inverse
__global__ __launch_bounds__(256) void k_fft(
    const float* __restrict__ h_c, const float* __restrict__ fr, const float* __restrict__ fi,
    const float* __restrict__ frb, const float* __restrict__ fib, float* __restrict__ g_c)
{
  const int b = blockIdx.y;
  const int c2 = blockIdx.x;
  const int tid = threadIdx.x;

  __shared__ float re[2048];
  __shared__ float im[2048];
  __shared__ float twr[512];
  __shared__ float twi[512];

  for (int i = tid; i < 512; i += 256) {
    float ang = -6.283185307179586f * (float)i * (1.0f / 2048.0f);
    float sn, cs;
    sincosf(ang, &sn, &cs);
    twr[i] = cs; twi[i] = sn;
  }
  const float* hrow = h_c + ((size_t)(b * 128 + c2)) * T;
  for (int t = tid; t < 2048; t += 256) {
    re[t] = hrow[t];
    im[t] = 0.f;
  }
  __syncthreads();

  // ---- forward: 5 radix-4 DIF stages (span 2048..8) ----
#pragma unroll
  for (int m = 2048; m >= 8; m >>= 2) {
    const int q = m >> 2;
    const int f = 2048 / m;
#pragma unroll
    for (int k = tid; k < 512; k += 256) {
      int p = k & (q - 1);
      int g = k / q;
      int i0 = g * m + p, i1 = i0 + q, i2 = i0 + 2 * q, i3 = i0 + 3 * q;
      float a0r = re[i0], a0i = im[i0], a1r = re[i1], a1i = im[i1];
      float a2r = re[i2], a2i = im[i2], a3r = re[i3], a3i = im[i3];
      float s0r = a0r + a2r, s0i = a0i + a2i;
      float s1r = a0r - a2r, s1i = a0i - a2i;
      float s2r = a1r + a3r, s2i = a1i + a3i;
      float s3r = a1r - a3r, s3i = a1i - a3i;
      re[i0] = s0r + s2r; im[i0] = s0i + s2i;           // y0 = s0+s2
      float y1r = s1r + s3i, y1i = s1i - s3r;           // s1 - j*s3
      float y2r = s0r - s2r, y2i = s0i - s2i;           // s0 - s2
      float y3r = s1r - s3i, y3i = s1i + s3r;           // s1 + j*s3
      float w1r = twr[f * p], w1i = twi[f * p];
      float w2r = w1r * w1r - w1i * w1i, w2i = 2.f * w1r * w1i;
      float w3r = w2r * w1r - w2i * w1i, w3i = w2r * w1i + w2i * w1r;
      re[i1] = y1r * w1r - y1i * w1i; im[i1] = y1r * w1i + y1i * w1r;
      re[i2] = y2r * w2r - y2i * w2i; im[i2] = y2r * w2i + y2i * w2r;
      re[i3] = y3r * w3r - y3i * w3i; im[i3] = y3r * w3i + y3i * w3r;
    }
    __syncthreads();
  }
  // ---- final radix-2 stage (span 2, w = 1) ----
  for (int k = tid; k < 1024; k += 256) {
    int i0 = 2 * k, i1 = 2 * k + 1;
    float ur = re[i0], ui = im[i0], vr = re[i1], vi = im[i1];
    re[i0] = ur + vr; im[i0] = ui + vi;
    re[i1] = ur - vr; im[i1] = ui - vi;
  }
  __syncthreads();

  // ---- elementwise spectral filter (order-independent) ----
  const float SC = 0.022097086912079608f; // 1/sqrt(2048)
  const float fa = fr[c2 * 129];
  const float fb = fi[c2 * 129];
  const float fra = frb[c2];
  const float fia = fib[c2];
  for (int t = tid; t < 2048; t += 256) {
    float rr = re[t] * SC, ii = im[t] * SC;
    re[t] = fmaxf(rr * fa - ii * fb + fra, 0.f);
    im[t] = fmaxf(ii * fa + rr * fb + fia, 0.f);
  }
  __syncthreads();

  // ---- inverse: mirrored radix-2, then radix-4 spans 8..2048 with conj twiddles ----
  for (int k = tid; k < 1024; k += 256) {
    int i0 = 2 * k, i1 = 2 * k + 1;
    float ur = re[i0], ui = im[i0], vr = re[i1], vi = im[i1];
    re[i0] = ur + vr; im[i0] = ui + vi;
    re[i1] = ur - vr; im[i1] = ui - vi;
  }
  __syncthreads();
#pragma unroll
  for (int m = 8; m <= 2048; m <<= 2) {
    const int q = m >> 2;
    const int f = 2048 / m;
#pragma unroll
    for (int k = tid; k < 512; k += 256) {
      int p = k & (q - 1);
      int g = k / q;
      int i0 = g * m + p, i1 = i0 + q, i2 = i0 + 2 * q, i3 = i0 + 3 * q;
      float y0r = re[i0], y0i = im[i0];
      float b1r = re[i1], b1i = im[i1];
      float b2r = re[i2], b2i = im[i2];
      float b3r = re[i3], b3i = im[i3];
      float w1r = twr[f * p], w1i = twi[f * p];
      float w2r = w1r * w1r - w1i * w1i, w2i = 2.f * w1r * w1i;
      float w3r = w2r * w1r - w2i * w1i, w3i = w2r * w1i + w2i * w1r;
      // z = b * conj(w)
      float z1r = b1r * w1r + b1i * w1i, z1i = b1i * w1r - b1r * w1i;
      float z2r = b2r * w2r + b2i * w2i, z2i = b2i * w2r - b2r * w2i;
      float z3r = b3r * w3r + b3i * w3i, z3i = b3i * w3r - b3r * w3i;
      float u0r = y0r + z2r, u0i = y0i + z2i;   // 2*s0
      float u2r = y0r - z2r, u2i = y0i - z2i;   // 2*s2
      float u1r = z1r + z3r, u1i = z1i + z3i;   // 2*s1
      float dr = z1r - z3r, di = z1i - z3i;     // -2j*s3
      float u3r = -di, u3i = dr;                // 2*s3 = j*(z1-z3)
      re[i0] = u0r + u1r; im[i0] = u0i + u1i;   // 4*a0
      re[i2] = u0r - u1r; im[i2] = u0i - u1i;   // 4*a2
      re[i1] = u2r + u3r; im[i1] = u2i + u3i;   // 4*a1
      re[i3] = u2r - u3r; im[i3] = u2i - u3i;   // 4*a3
    }
    __syncthreads();
  }

  float* grow = g_c + ((size_t)(b * 128 + c2)) * T;
  for (int t = tid; t < 2048; t += 256)
    grow[t] = re[t] * SC;
}

// ---------------------------------------------------------------- kernel 6: fc2 + bn + final residual -> d_out (B,64,T)
__global__ __launch_bounds__(256) void k_out(
    const float* __restrict__ g_c, const float* __restrict__ xres,
    const float* __restrict__ fc2_w, const float* __restrict__ bn2_g, const float* __restrict__ bn2_b,
    float* __restrict__ out)
{
  const int b = blockIdx.y;
  const int t0 = blockIdx.x * 16;
  const int tid = threadIdx.x;
  const float INVS = bnscale();

  __shared__ float gl[16][129];
  __shared__ float w2[128][65];   // fc2_w transposed: w2[cc][c]
  __shared__ float res[64][17];

  for (int i = tid; i < 2048; i += 256) {
    int tt = i & 15, cc = i >> 4;
    gl[tt][cc] = g_c[((size_t)(b * 128 + cc)) * T + t0 + tt];
  }
  for (int i = tid; i < 8192; i += 256) {
    int c = i >> 7, cc = i & 127;
    w2[cc][c] = fc2_w[i];
  }
  __syncthreads();

  {
    const int c = tid & 63, grp = tid >> 6;
    float a0 = 0.f, a1 = 0.f, a2 = 0.f, a3 = 0.f;
    for (int cc = 0; cc < 128; ++cc) {
      float wv = w2[cc][c];
      a0 += wv * gl[grp * 4 + 0][cc];
      a1 += wv * gl[grp * 4 + 1][cc];
      a2 += wv * gl[grp * 4 + 2][cc];
      a3 += wv * gl[grp * 4 + 3][cc];
    }
    float g2 = bn2_g[c] * INVS, b2 = bn2_b[c];
    float av[4] = {a0, a1, a2, a3};
#pragma unroll
    for (int j = 0; j < 4; ++j) {
      int tt = grp * 4 + j;
      res[c][tt] = xres[((size_t)(b * T + t0 + tt)) * 64 + c] + av[j] * g2 + b2;
    }
  }
  __syncthreads();

  for (int i = tid; i < 1024; i += 256) {
    int tt = i & 15, c = i >> 4;
    out[(size_t)(b * 64 + c) * T + t0 + tt] = res[c][tt];
  }
}

// ----------------------------------------------------------------
extern "C" void kernel_launch(void* const* d_in, const int* in_sizes, int n_in,
                              void* d_out, int out_size, void* d_ws, size_t ws_size,
                              hipStream_t stream) {
  (void)in_sizes; (void)n_in; (void)out_size; (void)ws_size;
  const float* x     = (const float*)d_in[0];
  const float* n1_g  = (const float*)d_in[1];
  const float* n1_b  = (const float*)d_in[2];
  const float* wq    = (const float*)d_in[3];
  const float* bnq_g = (const float*)d_in[4];
  const float* bnq_b = (const float*)d_in[5];
  const float* wk    = (const float*)d_in[6];
  const float* bnk_g = (const float*)d_in[7];
  const float* bnk_b = (const float*)d_in[8];
  const float* wv    = (const float*)d_in[9];
  const float* lepe_w= (const float*)d_in[10];
  const float* lepe_b= (const float*)d_in[11];
  const float* out_w = (const float*)d_in[12];
  const float* out_b = (const float*)d_in[13];
  const float* n2_g  = (const float*)d_in[14];
  const float* n2_b  = (const float*)d_in[15];
  const float* fc1_w = (const float*)d_in[16];
  const float* bn1_g = (const float*)d_in[17];
  const float* bn1_b = (const float*)d_in[18];
  const float* fr    = (const float*)d_in[19];
  const float* fi    = (const float*)d_in[20];
  const float* frb   = (const float*)d_in[21];
  const float* fib   = (const float*)d_in[22];
  const float* fc2_w = (const float*)d_in[23];
  const float* bn2_g = (const float*)d_in[24];
  const float* bn2_b = (const float*)d_in[25];

  float* out = (float*)d_out;
  float* ws  = (float*)d_ws;
  const size_t M1 = (size_t)1 << 20;

  float* q_t  = ws;            // 2M floats
  float* k_t  = ws + 2 * M1;   // 2M
  float* v_t  = ws + 4 * M1;   // 2M
  float* q_rc = ws + 6 * M1;   // 1M  (c-major [b][c][r])
  float* k_rc = ws + 7 * M1;   // 1M
  float* o_t  = ws + 8 * M1;   // 2M
  float* xrs  = ws + 10 * M1;  // 2M
  int*   sel  = (int*)(ws + 12 * M1); // 0.64M ints
  float* h_c  = ws;            // 4M c-major [b][cc][t], reuses q_t+k_t (dead after k_attn)
  float* g_c  = ws + 4 * M1;   // 4M c-major, reuses v_t+q_rc+k_rc

  k_qkv<<<dim3(128, 16), 256, 0, stream>>>(x, n1_g, n1_b, wq, bnq_g, bnq_b,
                                           wk, bnk_g, bnk_b, wv, q_t, k_t, v_t, q_rc, k_rc);
  k_scores<<<dim3(1024), 256, 0, stream>>>(q_rc, k_rc, sel);
  k_attn<<<dim3(16384), 256, 0, stream>>>(q_t, k_t, v_t, sel, lepe_w, lepe_b, o_t);
  k_mix<<<dim3(128, 16), 256, 0, stream>>>(x, o_t, out_w, out_b, n2_g, n2_b,
                                           fc1_w, bn1_g, bn1_b, xrs, h_c);
  k_fft<<<dim3(128, 16), 256, 0, stream>>>(h_c, fr, fi, frb, fib, g_c);
  k_out<<<dim3(128, 16), 256, 0, stream>>>(g_c, xrs, fc2_w, bn2_g, bn2_b, out);
}

// Round 12
// 420.182 us; speedup vs baseline: 1.0626x; 1.0626x over previous
//
#include <hip/hip_runtime.h>
#include <hip/hip_bf16.h>

#define T 2048
#define NR 1024
#define TOPK 40

static __device__ __forceinline__ float bnscale() { return 0.9999950000374997f; } // 1/sqrt(1+1e-5)

// ---------------------------------------------------------------- kernel 1: bn -> conv q,k (k=3) + v (k=1)
__global__ __launch_bounds__(256) void k_qkv(
    const float* __restrict__ x, const float* __restrict__ n1_g, const float* __restrict__ n1_b,
    const float* __restrict__ wq, const float* __restrict__ bnq_g, const float* __restrict__ bnq_b,
    const float* __restrict__ wk, const float* __restrict__ bnk_g, const float* __restrict__ bnk_b,
    const float* __restrict__ wv,
    float* __restrict__ q_t, float* __restrict__ k_t, float* __restrict__ v_t,
    float* __restrict__ q_rc, float* __restrict__ k_rc)
{
  const int b = blockIdx.y;
  const int tile = blockIdx.x >> 2;
  const int oc0 = (blockIdx.x & 3) * 16;
  const int t0 = tile * 64;
  const int r0 = tile * 32;
  const int tid = threadIdx.x;
  const float INVS = bnscale();

  __shared__ float xn[64][67];   // [c][tt], tt covers t0-1 .. t0+64
  __shared__ float ot[16][67];   // [oc_local][t_local]

  for (int i = tid; i < 64 * 66; i += 256) {
    int c = i / 66, tt = i - c * 66;
    int t = t0 + tt - 1;
    float v = (t >= 0 && t < T) ? x[(size_t)(b * 64 + c) * T + t] : 0.f;
    xn[c][tt] = v * (n1_g[c] * INVS) + n1_b[c];
  }
  __syncthreads();

  const int w = tid >> 6, lane = tid & 63;
  const int ob = oc0 + __builtin_amdgcn_readfirstlane(w) * 4;  // wave-uniform -> SGPR weight loads

  float accq[4], acck[4], accv[4];
#pragma unroll
  for (int j = 0; j < 4; ++j) { accq[j] = 0.f; acck[j] = 0.f; accv[j] = 0.f; }

#pragma unroll 1
  for (int c0 = 0; c0 < 64; c0 += 4) {
    float xr[4][3];
#pragma unroll
    for (int cc = 0; cc < 4; ++cc) {
      xr[cc][0] = xn[c0 + cc][lane];
      xr[cc][1] = xn[c0 + cc][lane + 1];
      xr[cc][2] = xn[c0 + cc][lane + 2];
    }
#pragma unroll
    for (int o4 = 0; o4 < 4; ++o4) {
      int o = ob + o4;
      const float* wqo = wq + o * 192 + c0 * 3;
      const float* wko = wk + o * 192 + c0 * 3;
      const float* wvo = wv + o * 64 + c0;
      float aq = accq[o4], ak = acck[o4], av = accv[o4];
#pragma unroll
      for (int cc = 0; cc < 4; ++cc) {
        aq += xr[cc][0] * wqo[cc * 3 + 0] + xr[cc][1] * wqo[cc * 3 + 1] + xr[cc][2] * wqo[cc * 3 + 2];
        ak += xr[cc][0] * wko[cc * 3 + 0] + xr[cc][1] * wko[cc * 3 + 1] + xr[cc][2] * wko[cc * 3 + 2];
        av += xr[cc][1] * wvo[cc];
      }
      accq[o4] = aq; acck[o4] = ak; accv[o4] = av;
    }
  }

  // ---- Q: bn, transpose-store slice, region means ----
#pragma unroll
  for (int o4 = 0; o4 < 4; ++o4) {
    int o = ob + o4;
    ot[o - oc0][lane] = accq[o4] * (bnq_g[o] * INVS) + bnq_b[o];
  }
  __syncthreads();
  for (int i = tid; i < 1024; i += 256) {
    int cl = i & 15, tt = i >> 4;
    q_t[((size_t)(b * T + t0 + tt)) * 64 + oc0 + cl] = ot[cl][tt];
  }
  for (int i = tid; i < 512; i += 256) {
    int rr = i & 31, cl = i >> 5;
    q_rc[((size_t)(b * 64 + oc0 + cl)) * NR + r0 + rr] = 0.5f * (ot[cl][2 * rr] + ot[cl][2 * rr + 1]);
  }
  __syncthreads();

  // ---- K ----
#pragma unroll
  for (int o4 = 0; o4 < 4; ++o4) {
    int o = ob + o4;
    ot[o - oc0][lane] = acck[o4] * (bnk_g[o] * INVS) + bnk_b[o];
  }
  __syncthreads();
  for (int i = tid; i < 1024; i += 256) {
    int cl = i & 15, tt = i >> 4;
    k_t[((size_t)(b * T + t0 + tt)) * 64 + oc0 + cl] = ot[cl][tt];
  }
  for (int i = tid; i < 512; i += 256) {
    int rr = i & 31, cl = i >> 5;
    k_rc[((size_t)(b * 64 + oc0 + cl)) * NR + r0 + rr] = 0.5f * (ot[cl][2 * rr] + ot[cl][2 * rr + 1]);
  }
  __syncthreads();

  // ---- V ----
#pragma unroll
  for (int o4 = 0; o4 < 4; ++o4) {
    ot[ob + o4 - oc0][lane] = accv[o4];
  }
  __syncthreads();
  for (int i = tid; i < 1024; i += 256) {
    int cl = i & 15, tt = i >> 4;
    v_t[((size_t)(b * T + t0 + tt)) * 64 + oc0 + cl] = ot[cl][tt];
  }
}

// ---------------------------------------------------------------- kernel 2: region scores + top-40
// v9: v6 (ballot-quickselect + XCD swizzle, proven best structure at 88.5us) with ONE change:
// c0 loop unroll 1 -> 2 so the compiler can software-pipeline across iterations (32 loads in
// flight vs 16, 512 independent FMAs between waits). Targets the measured latency bubble
// (VALUBusy 34% vs ~20us of issue work). No LDS staging, no barriers, no mapping change
// (v7/v8 restructurings both regressed).
__global__ __launch_bounds__(256) void k_scores(
    const float* __restrict__ q_rc, const float* __restrict__ k_rc, int* __restrict__ sel)
{
  const int ib = blockIdx.x;
  const int xcd = ib & 7;
  const int slot = ib >> 3;             // 0..127
  const int b = xcd * 2 + (slot >> 6);  // 2 batches per XCD
  const int r0 = (slot & 63) * 16;
  const int tid = threadIdx.x;
  const int w = tid >> 6, lane = tid & 63;

  __shared__ float qsT[16][68];   // [row][c], pad 68 keeps float4 alignment, 2-way banks (free)

  for (int i = tid; i < 1024; i += 256) {
    int rr = i & 15, c = i >> 4;
    qsT[rr][c] = q_rc[((size_t)(b * 64 + c)) * NR + r0 + rr];
  }
  __syncthreads();

  const int row0 = w * 4;

  // ---- GEMM: wave computes rows r0+row0..+3; lane holds cols {256j + 4lane + s}
  float4 acc[4][4];
#pragma unroll
  for (int r = 0; r < 4; ++r)
#pragma unroll
    for (int j = 0; j < 4; ++j) acc[r][j] = make_float4(0.f, 0.f, 0.f, 0.f);

  const float4* kp = (const float4*)(k_rc + ((size_t)b * 64) * NR);
#pragma unroll 2
  for (int c0 = 0; c0 < 64; c0 += 4) {
    float4 qv[4];
#pragma unroll
    for (int r = 0; r < 4; ++r) qv[r] = *(const float4*)&qsT[row0 + r][c0];
#pragma unroll
    for (int cc = 0; cc < 4; ++cc) {
      const float4* kr = kp + (size_t)(c0 + cc) * 256 + lane;
      float4 k0 = kr[0], k1 = kr[64], k2 = kr[128], k3 = kr[192];
      float qf[4] = { (&qv[0].x)[cc], (&qv[1].x)[cc], (&qv[2].x)[cc], (&qv[3].x)[cc] };
#pragma unroll
      for (int r = 0; r < 4; ++r) {
        float q = qf[r];
        acc[r][0].x += q * k0.x; acc[r][0].y += q * k0.y; acc[r][0].z += q * k0.z; acc[r][0].w += q * k0.w;
        acc[r][1].x += q * k1.x; acc[r][1].y += q * k1.y; acc[r][1].z += q * k1.z; acc[r][1].w += q * k1.w;
        acc[r][2].x += q * k2.x; acc[r][2].y += q * k2.y; acc[r][2].z += q * k2.z; acc[r][2].w += q * k2.w;
        acc[r][3].x += q * k3.x; acc[r][3].y += q * k3.y; acc[r][3].z += q * k3.z; acc[r][3].w += q * k3.w;
      }
    }
  }

  // ---- pack to sortable u32: hi 22 = score (sign-flip trick), lo 10 = 1023-idx (unique) ----
  unsigned pk[4][16];
#pragma unroll
  for (int r = 0; r < 4; ++r) {
#pragma unroll
    for (int j = 0; j < 4; ++j) {
      const float* av = &acc[r][j].x;
#pragma unroll
      for (int s = 0; s < 4; ++s) {
        unsigned u = __float_as_uint(av[s]);
        u ^= (unsigned)((int)u >> 31) | 0x80000000u;
        int idx = 256 * j + 4 * lane + s;
        pk[r][4 * j + s] = (u & 0xFFFFFC00u) | (unsigned)(1023 - idx);
      }
    }
  }

  // ---- ballot-quickselect: per-row exactly-40 threshold via bit descent ----
  unsigned p[4] = {0u, 0u, 0u, 0u};
  unsigned thr[4];
  bool done[4] = {false, false, false, false};
#pragma unroll 1
  for (int bit = 31; bit >= 0; --bit) {
#pragma unroll
    for (int r = 0; r < 4; ++r) {
      if (done[r]) continue;                       // wave-uniform branch
      unsigned X = p[r] | (1u << bit);
      int c = 0;
#pragma unroll
      for (int j = 0; j < 16; ++j)
        c += __popcll(__ballot(pk[r][j] >= X));
      if (c >= TOPK) p[r] = X;
      if (c == TOPK) { thr[r] = X; done[r] = true; }
    }
    if (done[0] && done[1] && done[2] && done[3]) break;
  }
#pragma unroll
  for (int r = 0; r < 4; ++r)
    if (!done[r]) thr[r] = p[r];                   // invariant: count(v>=p) == 40 after full descent

  // ---- emit: ballot + mbcnt rank -> scatter (arbitrary order within the set) ----
#pragma unroll
  for (int r = 0; r < 4; ++r) {
    const unsigned X = thr[r];
    int* srow = sel + ((size_t)(b * NR + r0 + row0 + r)) * TOPK;
    int base = 0;
#pragma unroll
    for (int j = 0; j < 16; ++j) {
      bool win = pk[r][j] >= X;
      unsigned long long m = __ballot(win);
      int before = __builtin_amdgcn_mbcnt_hi((unsigned)(m >> 32),
                   __builtin_amdgcn_mbcnt_lo((unsigned)m, 0));
      if (win) srow[base + before] = 1023 - (int)(pk[r][j] & 1023u);
      base += __popcll(m);
    }
  }
}

// ---------------------------------------------------------------- kernel 3: gathered attention + lepe depthwise + bias
// v2: + XCD-locality swizzle (grid 1D 16384; each XCD owns 2 batches -> gathered K/V working
// set ~2 MB fits per-XCD L2).
__global__ __launch_bounds__(256) void k_attn(
    const float* __restrict__ q_t, const float* __restrict__ k_t, const float* __restrict__ v_t,
    const int* __restrict__ sel, const float* __restrict__ lepe_w, const float* __restrict__ lepe_b,
    float* __restrict__ o_t)
{
  const int ib = blockIdx.x;
  const int xcd = ib & 7;
  const int slot = ib >> 3;               // 0..2047
  const int b = xcd * 2 + (slot >> 10);   // 2 batches per XCD
  const int r = slot & 1023;
  const int tid = threadIdx.x;

  __shared__ __align__(16) float kg[80][68];   // gathered K, 21.76 KB, rows 16B-aligned
  __shared__ __align__(16) float qb[2][64];
  __shared__ int   toff[80];                   // byte offset of gathered row within (b) plane
  __shared__ __align__(16) float lg[4][2][84]; // probs per head
  __shared__ float vl[4][64];                  // v rows 2r-1..2r+2 for lepe

  // part[half][sq][c] aliases kg (dead after QK^T)
  float (*part)[2][64] = (float (*)[2][64])&kg[0][0];

  if (tid < 40) {
    int s = sel[((size_t)(b * NR + r)) * TOPK + tid];
    toff[2 * tid]     = s * 512;        // row 2s   * 64 floats * 4 B
    toff[2 * tid + 1] = s * 512 + 256;  // row 2s+1
  }
  if (tid >= 128 && tid < 256) {
    int i = tid - 128;
    int s = i >> 6, c = i & 63;
    qb[s][c] = q_t[((size_t)(b * T + r * 2 + s)) * 64 + c];
  }
  {
    int idx = tid >> 6, c = tid & 63;
    int t = 2 * r - 1 + idx;
    vl[idx][c] = (t >= 0 && t < T) ? v_t[((size_t)(b * T + t)) * 64 + c] : 0.f;
  }
  __syncthreads();

  // ---- stage gathered K with float4 (5 iters/thread) ----
  {
    const char* kbase = (const char*)(k_t + (size_t)b * T * 64);
    for (int i = tid; i < 80 * 16; i += 256) {
      int row = i >> 4, c4 = i & 15;
      float4 kv = *(const float4*)(kbase + toff[row] + c4 * 16);
      *(float4*)&kg[row][c4 * 4] = kv;
    }
  }
  __syncthreads();

  const int h = tid >> 6, lane = tid & 63;

  // ---- QK^T: Q in registers, each gathered K row read once as 4 x b128, both sq per col ----
  {
    float4 q0[4], q1[4];
#pragma unroll
    for (int j = 0; j < 4; ++j) {
      q0[j] = *(const float4*)&qb[0][h * 16 + j * 4];
      q1[j] = *(const float4*)&qb[1][h * 16 + j * 4];
    }
    for (int col = lane; col < 80; col += 64) {
      float a0 = 0.f, a1 = 0.f;
#pragma unroll
      for (int j = 0; j < 4; ++j) {
        float4 kv = *(const float4*)&kg[col][h * 16 + j * 4];
        a0 += q0[j].x * kv.x + q0[j].y * kv.y + q0[j].z * kv.z + q0[j].w * kv.w;
        a1 += q1[j].x * kv.x + q1[j].y * kv.y + q1[j].z * kv.z + q1[j].w * kv.w;
      }
      lg[h][0][col] = a0 * 0.125f;  // 64^-0.5
      lg[h][1][col] = a1 * 0.125f;
    }
  }

  // ---- softmax (wave-local: lg[h] written and read by wave h only) ----
  for (int sq = 0; sq < 2; ++sq) {
    float a = lg[h][sq][lane];
    float bb = (lane < 16) ? lg[h][sq][64 + lane] : -INFINITY;
    float m = fmaxf(a, bb);
    for (int mm = 32; mm >= 1; mm >>= 1) m = fmaxf(m, __shfl_xor(m, mm));
    float ea = expf(a - m);
    float eb = (lane < 16) ? expf(bb - m) : 0.f;
    float ssum = ea + eb;
    for (int mm = 32; mm >= 1; mm >>= 1) ssum += __shfl_xor(ssum, mm);
    float inv = 1.f / ssum;
    lg[h][sq][lane] = ea * inv;
    if (lane < 16) lg[h][sq][64 + lane] = eb * inv;
  }
  __syncthreads();   // lg complete across heads; kg now dead -> part may reuse it

  // ---- PV: thread = (half, sq, c); p as float4, V rows coalesced from global (L2-hit) ----
  {
    const int c = tid & 63, j = tid >> 6;
    const int sq = j & 1, half = j >> 1;
    const int hh = c >> 4;
    const char* vbase = (const char*)(v_t + (size_t)b * T * 64) + c * 4;
    float acc = 0.f;
#pragma unroll 2
    for (int ch = 0; ch < 10; ++ch) {
      int col0 = half * 40 + ch * 4;
      float4 p = *(const float4*)&lg[hh][sq][col0];
      float v0 = *(const float*)(vbase + toff[col0 + 0]);
      float v1 = *(const float*)(vbase + toff[col0 + 1]);
      float v2 = *(const float*)(vbase + toff[col0 + 2]);
      float v3 = *(const float*)(vbase + toff[col0 + 3]);
      acc += p.x * v0 + p.y * v1 + p.z * v2 + p.w * v3;
    }
    part[half][sq][c] = acc;
  }
  __syncthreads();

  if (tid < 128) {
    int sq = tid >> 6, c = tid & 63;
    float o = part[0][sq][c] + part[1][sq][c];
    float lep = lepe_b[c];
#pragma unroll
    for (int kk = 0; kk < 3; ++kk) lep += lepe_w[c * 3 + kk] * vl[sq + kk][c];
    o_t[((size_t)(b * T + 2 * r + sq)) * 64 + c] = o + lep;
  }
}

// ---------------------------------------------------------------- kernel 4: out conv + residual + bn2 + fc1 + relu -> h_c (c-major)
__global__ __launch_bounds__(256) void k_mix(
    const float* __restrict__ x, const float* __restrict__ o_t,
    const float* __restrict__ out_w, const float* __restrict__ out_b,
    const float* __restrict__ n2_g, const float* __restrict__ n2_b,
    const float* __restrict__ fc1_w, const float* __restrict__ bn1_g, const float* __restrict__ bn1_b,
    float* __restrict__ xres, float* __restrict__ h_c)
{
  const int b = blockIdx.y;
  const int t0 = blockIdx.x * 16;
  const int tid = threadIdx.x;
  const float INVS = bnscale();

  __shared__ float ol[16][65];
  __shared__ float yn[16][65];
  __shared__ float xl[16][65];
  __shared__ float wo[64][65];    // out_w transposed: wo[cc][c]
  __shared__ float w1[128][65];   // fc1_w natural [cc][c]
  __shared__ float res2[128][17];

  for (int i = tid; i < 1024; i += 256) {
    int tt = i >> 6, c = i & 63;
    ol[tt][c] = o_t[((size_t)(b * T + t0 + tt)) * 64 + c];
  }
  for (int i = tid; i < 1024; i += 256) {
    int c = i >> 4, tt = i & 15;
    xl[tt][c] = x[(size_t)(b * 64 + c) * T + t0 + tt];
  }
  for (int i = tid; i < 4096; i += 256) {
    int c = i >> 6, cc = i & 63;
    wo[cc][c] = out_w[i];
  }
  for (int i = tid; i < 8192; i += 256) {
    int cc = i >> 6, c = i & 63;
    w1[cc][c] = fc1_w[i];
  }
  __syncthreads();

  // out conv: thread = (c, 4 tt's)
  {
    const int c = tid & 63, grp = tid >> 6;
    float a0 = out_b[c], a1 = a0, a2 = a0, a3 = a0;
    for (int cc = 0; cc < 64; ++cc) {
      float wv = wo[cc][c];
      a0 += wv * ol[grp * 4 + 0][cc];
      a1 += wv * ol[grp * 4 + 1][cc];
      a2 += wv * ol[grp * 4 + 2][cc];
      a3 += wv * ol[grp * 4 + 3][cc];
    }
    float g2 = n2_g[c] * INVS, b2 = n2_b[c];
    float av[4] = {a0, a1, a2, a3};
#pragma unroll
    for (int j = 0; j < 4; ++j) {
      int tt = grp * 4 + j;
      float xr = xl[tt][c] + av[j];
      xres[((size_t)(b * T + t0 + tt)) * 64 + c] = xr;
      yn[tt][c] = xr * g2 + b2;
    }
  }
  __syncthreads();

  // fc1 + bn1 + relu: thread = (cc, 8 tt's)
  {
    const int cc = tid & 127, half = tid >> 7;
    float acc[8];
#pragma unroll
    for (int j = 0; j < 8; ++j) acc[j] = 0.f;
    for (int c = 0; c < 64; ++c) {
      float wv = w1[cc][c];
#pragma unroll
      for (int j = 0; j < 8; ++j) acc[j] += wv * yn[half * 8 + j][c];
    }
    float g1 = bn1_g[cc] * INVS, b1 = bn1_b[cc];
#pragma unroll
    for (int j = 0; j < 8; ++j)
      res2[cc][half * 8 + j] = fmaxf(acc[j] * g1 + b1, 0.f);
  }
  __syncthreads();

  for (int i = tid; i < 2048; i += 256) {
    int tt = i & 15, cc = i >> 4;
    h_c[((size_t)(b * 128 + cc)) * T + t0 + tt] = res2[cc][tt];
  }
}

// ---------------------------------------------------------------- kernel 5: FFT radix-4 (5 stages + radix-2) -> diag filter + relu -> mirrored inverse
__global__ __launch_bounds__(256) void k_fft(
    const float* __restrict__ h_c, const float* __restrict__ fr, const float* __restrict__ fi,
    const float* __restrict__ frb, const float* __restrict__ fib, float* __restrict__ g_c)
{
  const int b = blockIdx.y;
  const int c2 = blockIdx.x;
  const int tid = threadIdx.x;

  __shared__ float re[2048];
  __shared__ float im[2048];
  __shared__ float twr[512];
  __shared__ float twi[512];

  for (int i = tid; i < 512; i += 256) {
    float ang = -6.283185307179586f * (float)i * (1.0f / 2048.0f);
    float sn, cs;
    sincosf(ang, &sn, &cs);
    twr[i] = cs; twi[i] = sn;
  }
  const float* hrow = h_c + ((size_t)(b * 128 + c2)) * T;
  for (int t = tid; t < 2048; t += 256) {
    re[t] = hrow[t];
    im[t] = 0.f;
  }
  __syncthreads();

  // ---- forward: 5 radix-4 DIF stages (span 2048..8) ----
#pragma unroll
  for (int m = 2048; m >= 8; m >>= 2) {
    const int q = m >> 2;
    const int f = 2048 / m;
#pragma unroll
    for (int k = tid; k < 512; k += 256) {
      int p = k & (q - 1);
      int g = k / q;
      int i0 = g * m + p, i1 = i0 + q, i2 = i0 + 2 * q, i3 = i0 + 3 * q;
      float a0r = re[i0], a0i = im[i0], a1r = re[i1], a1i = im[i1];
      float a2r = re[i2], a2i = im[i2], a3r = re[i3], a3i = im[i3];
      float s0r = a0r + a2r, s0i = a0i + a2i;
      float s1r = a0r - a2r, s1i = a0i - a2i;
      float s2r = a1r + a3r, s2i = a1i + a3i;
      float s3r = a1r - a3r, s3i = a1i - a3i;
      re[i0] = s0r + s2r; im[i0] = s0i + s2i;           // y0 = s0+s2
      float y1r = s1r + s3i, y1i = s1i - s3r;           // s1 - j*s3
      float y2r = s0r - s2r, y2i = s0i - s2i;           // s0 - s2
      float y3r = s1r - s3i, y3i = s1i + s3r;           // s1 + j*s3
      float w1r = twr[f * p], w1i = twi[f * p];
      float w2r = w1r * w1r - w1i * w1i, w2i = 2.f * w1r * w1i;
      float w3r = w2r * w1r - w2i * w1i, w3i = w2r * w1i + w2i * w1r;
      re[i1] = y1r * w1r - y1i * w1i; im[i1] = y1r * w1i + y1i * w1r;
      re[i2] = y2r * w2r - y2i * w2i; im[i2] = y2r * w2i + y2i * w2r;
      re[i3] = y3r * w3r - y3i * w3i; im[i3] = y3r * w3i + y3i * w3r;
    }
    __syncthreads();
  }
  // ---- final radix-2 stage (span 2, w = 1) ----
  for (int k = tid; k < 1024; k += 256) {
    int i0 = 2 * k, i1 = 2 * k + 1;
    float ur = re[i0], ui = im[i0], vr = re[i1], vi = im[i1];
    re[i0] = ur + vr; im[i0] = ui + vi;
    re[i1] = ur - vr; im[i1] = ui - vi;
  }
  __syncthreads();

  // ---- elementwise spectral filter (order-independent) ----
  const float SC = 0.022097086912079608f; // 1/sqrt(2048)
  const float fa = fr[c2 * 129];
  const float fb = fi[c2 * 129];
  const float fra = frb[c2];
  const float fia = fib[c2];
  for (int t = tid; t < 2048; t += 256) {
    float rr = re[t] * SC, ii = im[t] * SC;
    re[t] = fmaxf(rr * fa - ii * fb + fra, 0.f);
    im[t] = fmaxf(ii * fa + rr * fb + fia, 0.f);
  }
  __syncthreads();

  // ---- inverse: mirrored radix-2, then radix-4 spans 8..2048 with conj twiddles ----
  for (int k = tid; k < 1024; k += 256) {
    int i0 = 2 * k, i1 = 2 * k + 1;
    float ur = re[i0], ui = im[i0], vr = re[i1], vi = im[i1];
    re[i0] = ur + vr; im[i0] = ui + vi;
    re[i1] = ur - vr; im[i1] = ui - vi;
  }
  __syncthreads();
#pragma unroll
  for (int m = 8; m <= 2048; m <<= 2) {
    const int q = m >> 2;
    const int f = 2048 / m;
#pragma unroll
    for (int k = tid; k < 512; k += 256) {
      int p = k & (q - 1);
      int g = k / q;
      int i0 = g * m + p, i1 = i0 + q, i2 = i0 + 2 * q, i3 = i0 + 3 * q;
      float y0r = re[i0], y0i = im[i0];
      float b1r = re[i1], b1i = im[i1];
      float b2r = re[i2], b2i = im[i2];
      float b3r = re[i3], b3i = im[i3];
      float w1r = twr[f * p], w1i = twi[f * p];
      float w2r = w1r * w1r - w1i * w1i, w2i = 2.f * w1r * w1i;
      float w3r = w2r * w1r - w2i * w1i, w3i = w2r * w1i + w2i * w1r;
      // z = b * conj(w)
      float z1r = b1r * w1r + b1i * w1i, z1i = b1i * w1r - b1r * w1i;
      float z2r = b2r * w2r + b2i * w2i, z2i = b2i * w2r - b2r * w2i;
      float z3r = b3r * w3r + b3i * w3i, z3i = b3i * w3r - b3r * w3i;
      float u0r = y0r + z2r, u0i = y0i + z2i;   // 2*s0
      float u2r = y0r - z2r, u2i = y0i - z2i;   // 2*s2
      float u1r = z1r + z3r, u1i = z1i + z3i;   // 2*s1
      float dr = z1r - z3r, di = z1i - z3i;     // -2j*s3
      float u3r = -di, u3i = dr;                // 2*s3 = j*(z1-z3)
      re[i0] = u0r + u1r; im[i0] = u0i + u1i;   // 4*a0
      re[i2] = u0r - u1r; im[i2] = u0i - u1i;   // 4*a2
      re[i1] = u2r + u3r; im[i1] = u2i + u3i;   // 4*a1
      re[i3] = u2r - u3r; im[i3] = u2i - u3i;   // 4*a3
    }
    __syncthreads();
  }

  float* grow = g_c + ((size_t)(b * 128 + c2)) * T;
  for (int t = tid; t < 2048; t += 256)
    grow[t] = re[t] * SC;
}

// ---------------------------------------------------------------- kernel 6: fc2 + bn + final residual -> d_out (B,64,T)
__global__ __launch_bounds__(256) void k_out(
    const float* __restrict__ g_c, const float* __restrict__ xres,
    const float* __restrict__ fc2_w, const float* __restrict__ bn2_g, const float* __restrict__ bn2_b,
    float* __restrict__ out)
{
  const int b = blockIdx.y;
  const int t0 = blockIdx.x * 16;
  const int tid = threadIdx.x;
  const float INVS = bnscale();

  __shared__ float gl[16][129];
  __shared__ float w2[128][65];   // fc2_w transposed: w2[cc][c]
  __shared__ float res[64][17];

  for (int i = tid; i < 2048; i += 256) {
    int tt = i & 15, cc = i >> 4;
    gl[tt][cc] = g_c[((size_t)(b * 128 + cc)) * T + t0 + tt];
  }
  for (int i = tid; i < 8192; i += 256) {
    int c = i >> 7, cc = i & 127;
    w2[cc][c] = fc2_w[i];
  }
  __syncthreads();

  {
    const int c = tid & 63, grp = tid >> 6;
    float a0 = 0.f, a1 = 0.f, a2 = 0.f, a3 = 0.f;
    for (int cc = 0; cc < 128; ++cc) {
      float wv = w2[cc][c];
      a0 += wv * gl[grp * 4 + 0][cc];
      a1 += wv * gl[grp * 4 + 1][cc];
      a2 += wv * gl[grp * 4 + 2][cc];
      a3 += wv * gl[grp * 4 + 3][cc];
    }
    float g2 = bn2_g[c] * INVS, b2 = bn2_b[c];
    float av[4] = {a0, a1, a2, a3};
#pragma unroll
    for (int j = 0; j < 4; ++j) {
      int tt = grp * 4 + j;
      res[c][tt] = xres[((size_t)(b * T + t0 + tt)) * 64 + c] + av[j] * g2 + b2;
    }
  }
  __syncthreads();

  for (int i = tid; i < 1024; i += 256) {
    int tt = i & 15, c = i >> 4;
    out[(size_t)(b * 64 + c) * T + t0 + tt] = res[c][tt];
  }
}

// ----------------------------------------------------------------
extern "C" void kernel_launch(void* const* d_in, const int* in_sizes, int n_in,
                              void* d_out, int out_size, void* d_ws, size_t ws_size,
                              hipStream_t stream) {
  (void)in_sizes; (void)n_in; (void)out_size; (void)ws_size;
  const float* x     = (const float*)d_in[0];
  const float* n1_g  = (const float*)d_in[1];
  const float* n1_b  = (const float*)d_in[2];
  const float* wq    = (const float*)d_in[3];
  const float* bnq_g = (const float*)d_in[4];
  const float* bnq_b = (const float*)d_in[5];
  const float* wk    = (const float*)d_in[6];
  const float* bnk_g = (const float*)d_in[7];
  const float* bnk_b = (const float*)d_in[8];
  const float* wv    = (const float*)d_in[9];
  const float* lepe_w= (const float*)d_in[10];
  const float* lepe_b= (const float*)d_in[11];
  const float* out_w = (const float*)d_in[12];
  const float* out_b = (const float*)d_in[13];
  const float* n2_g  = (const float*)d_in[14];
  const float* n2_b  = (const float*)d_in[15];
  const float* fc1_w = (const float*)d_in[16];
  const float* bn1_g = (const float*)d_in[17];
  const float* bn1_b = (const float*)d_in[18];
  const float* fr    = (const float*)d_in[19];
  const float* fi    = (const float*)d_in[20];
  const float* frb   = (const float*)d_in[21];
  const float* fib   = (const float*)d_in[22];
  const float* fc2_w = (const float*)d_in[23];
  const float* bn2_g = (const float*)d_in[24];
  const float* bn2_b = (const float*)d_in[25];

  float* out = (float*)d_out;
  float* ws  = (float*)d_ws;
  const size_t M1 = (size_t)1 << 20;

  float* q_t  = ws;            // 2M floats
  float* k_t  = ws + 2 * M1;   // 2M
  float* v_t  = ws + 4 * M1;   // 2M
  float* q_rc = ws + 6 * M1;   // 1M  (c-major [b][c][r])
  float* k_rc = ws + 7 * M1;   // 1M
  float* o_t  = ws + 8 * M1;   // 2M
  float* xrs  = ws + 10 * M1;  // 2M
  int*   sel  = (int*)(ws + 12 * M1); // 0.64M ints
  float* h_c  = ws;            // 4M c-major [b][cc][t], reuses q_t+k_t (dead after k_attn)
  float* g_c  = ws + 4 * M1;   // 4M c-major, reuses v_t+q_rc+k_rc

  k_qkv<<<dim3(128, 16), 256, 0, stream>>>(x, n1_g, n1_b, wq, bnq_g, bnq_b,
                                           wk, bnk_g, bnk_b, wv, q_t, k_t, v_t, q_rc, k_rc);
  k_scores<<<dim3(1024), 256, 0, stream>>>(q_rc, k_rc, sel);
  k_attn<<<dim3(16384), 256, 0, stream>>>(q_t, k_t, v_t, sel, lepe_w, lepe_b, o_t);
  k_mix<<<dim3(128, 16), 256, 0, stream>>>(x, o_t, out_w, out_b, n2_g, n2_b,
                                           fc1_w, bn1_g, bn1_b, xrs, h_c);
  k_fft<<<dim3(128, 16), 256, 0, stream>>>(h_c, fr, fi, frb, fib, g_c);
  k_out<<<dim3(128, 16), 256, 0, stream>>>(g_c, xrs, fc2_w, bn2_g, bn2_b, out);
}

// Round 13
// 416.872 us; speedup vs baseline: 1.0711x; 1.0079x over previous
//
#include <hip/hip_runtime.h>
#include <hip/hip_bf16.h>

#define T 2048
#define NR 1024
#define TOPK 40

static __device__ __forceinline__ float bnscale() { return 0.9999950000374997f; } // 1/sqrt(1+1e-5)

// ---------------------------------------------------------------- kernel 1: bn -> conv q,k (k=3) + v (k=1)
__global__ __launch_bounds__(256) void k_qkv(
    const float* __restrict__ x, const float* __restrict__ n1_g, const float* __restrict__ n1_b,
    const float* __restrict__ wq, const float* __restrict__ bnq_g, const float* __restrict__ bnq_b,
    const float* __restrict__ wk, const float* __restrict__ bnk_g, const float* __restrict__ bnk_b,
    const float* __restrict__ wv,
    float* __restrict__ q_t, float* __restrict__ k_t, float* __restrict__ v_t,
    float* __restrict__ q_rc, float* __restrict__ k_rc)
{
  const int b = blockIdx.y;
  const int tile = blockIdx.x >> 2;
  const int oc0 = (blockIdx.x & 3) * 16;
  const int t0 = tile * 64;
  const int r0 = tile * 32;
  const int tid = threadIdx.x;
  const float INVS = bnscale();

  __shared__ float xn[64][67];   // [c][tt], tt covers t0-1 .. t0+64
  __shared__ float ot[16][67];   // [oc_local][t_local]

  for (int i = tid; i < 64 * 66; i += 256) {
    int c = i / 66, tt = i - c * 66;
    int t = t0 + tt - 1;
    float v = (t >= 0 && t < T) ? x[(size_t)(b * 64 + c) * T + t] : 0.f;
    xn[c][tt] = v * (n1_g[c] * INVS) + n1_b[c];
  }
  __syncthreads();

  const int w = tid >> 6, lane = tid & 63;
  const int ob = oc0 + __builtin_amdgcn_readfirstlane(w) * 4;  // wave-uniform -> SGPR weight loads

  float accq[4], acck[4], accv[4];
#pragma unroll
  for (int j = 0; j < 4; ++j) { accq[j] = 0.f; acck[j] = 0.f; accv[j] = 0.f; }

#pragma unroll 1
  for (int c0 = 0; c0 < 64; c0 += 4) {
    float xr[4][3];
#pragma unroll
    for (int cc = 0; cc < 4; ++cc) {
      xr[cc][0] = xn[c0 + cc][lane];
      xr[cc][1] = xn[c0 + cc][lane + 1];
      xr[cc][2] = xn[c0 + cc][lane + 2];
    }
#pragma unroll
    for (int o4 = 0; o4 < 4; ++o4) {
      int o = ob + o4;
      const float* wqo = wq + o * 192 + c0 * 3;
      const float* wko = wk + o * 192 + c0 * 3;
      const float* wvo = wv + o * 64 + c0;
      float aq = accq[o4], ak = acck[o4], av = accv[o4];
#pragma unroll
      for (int cc = 0; cc < 4; ++cc) {
        aq += xr[cc][0] * wqo[cc * 3 + 0] + xr[cc][1] * wqo[cc * 3 + 1] + xr[cc][2] * wqo[cc * 3 + 2];
        ak += xr[cc][0] * wko[cc * 3 + 0] + xr[cc][1] * wko[cc * 3 + 1] + xr[cc][2] * wko[cc * 3 + 2];
        av += xr[cc][1] * wvo[cc];
      }
      accq[o4] = aq; acck[o4] = ak; accv[o4] = av;
    }
  }

  // ---- Q: bn, transpose-store slice, region means ----
#pragma unroll
  for (int o4 = 0; o4 < 4; ++o4) {
    int o = ob + o4;
    ot[o - oc0][lane] = accq[o4] * (bnq_g[o] * INVS) + bnq_b[o];
  }
  __syncthreads();
  for (int i = tid; i < 1024; i += 256) {
    int cl = i & 15, tt = i >> 4;
    q_t[((size_t)(b * T + t0 + tt)) * 64 + oc0 + cl] = ot[cl][tt];
  }
  for (int i = tid; i < 512; i += 256) {
    int rr = i & 31, cl = i >> 5;
    q_rc[((size_t)(b * 64 + oc0 + cl)) * NR + r0 + rr] = 0.5f * (ot[cl][2 * rr] + ot[cl][2 * rr + 1]);
  }
  __syncthreads();

  // ---- K ----
#pragma unroll
  for (int o4 = 0; o4 < 4; ++o4) {
    int o = ob + o4;
    ot[o - oc0][lane] = acck[o4] * (bnk_g[o] * INVS) + bnk_b[o];
  }
  __syncthreads();
  for (int i = tid; i < 1024; i += 256) {
    int cl = i & 15, tt = i >> 4;
    k_t[((size_t)(b * T + t0 + tt)) * 64 + oc0 + cl] = ot[cl][tt];
  }
  for (int i = tid; i < 512; i += 256) {
    int rr = i & 31, cl = i >> 5;
    k_rc[((size_t)(b * 64 + oc0 + cl)) * NR + r0 + rr] = 0.5f * (ot[cl][2 * rr] + ot[cl][2 * rr + 1]);
  }
  __syncthreads();

  // ---- V ----
#pragma unroll
  for (int o4 = 0; o4 < 4; ++o4) {
    ot[ob + o4 - oc0][lane] = accv[o4];
  }
  __syncthreads();
  for (int i = tid; i < 1024; i += 256) {
    int cl = i & 15, tt = i >> 4;
    v_t[((size_t)(b * T + t0 + tt)) * 64 + oc0 + cl] = ot[cl][tt];
  }
}

// ---------------------------------------------------------------- kernel 2: region scores + top-40
// v10: v6 per-wave structure (proven best: 4 rows/wave, full 1024 cols, ballot-quickselect,
// unroll 1 -- v7/v8/v9 restructurings all regressed) regrouped into 512-thread blocks:
// 8 waves/block share ONE byte-identical B stream through L1 (waves differ only in Q rows),
// halving per-CU L1-miss traffic (4x256KB -> 2x256KB) and doubling L1 temporal reuse.
// Grid 512 (2 blocks/CU, same 16 waves/CU). XCD swizzle: 64 slots/XCD = 2 batches x 32 tiles.
__global__ __launch_bounds__(512) void k_scores(
    const float* __restrict__ q_rc, const float* __restrict__ k_rc, int* __restrict__ sel)
{
  const int ib = blockIdx.x;
  const int xcd = ib & 7;
  const int slot = ib >> 3;             // 0..63
  const int b = xcd * 2 + (slot >> 5);  // 2 batches per XCD
  const int r0 = (slot & 31) * 32;      // 32 rows per block
  const int tid = threadIdx.x;
  const int w = tid >> 6, lane = tid & 63;

  __shared__ float qsT[32][68];   // [row][c], pad 68 keeps float4 alignment

  for (int i = tid; i < 2048; i += 512) {
    int rr = i & 31, c = i >> 5;
    qsT[rr][c] = q_rc[((size_t)(b * 64 + c)) * NR + r0 + rr];
  }
  __syncthreads();

  const int row0 = w * 4;

  // ---- GEMM: wave computes rows r0+row0..+3; lane holds cols {256j + 4lane + s}
  float4 acc[4][4];
#pragma unroll
  for (int r = 0; r < 4; ++r)
#pragma unroll
    for (int j = 0; j < 4; ++j) acc[r][j] = make_float4(0.f, 0.f, 0.f, 0.f);

  const float4* kp = (const float4*)(k_rc + ((size_t)b * 64) * NR);
#pragma unroll 1
  for (int c0 = 0; c0 < 64; c0 += 4) {
    float4 qv[4];
#pragma unroll
    for (int r = 0; r < 4; ++r) qv[r] = *(const float4*)&qsT[row0 + r][c0];
#pragma unroll
    for (int cc = 0; cc < 4; ++cc) {
      const float4* kr = kp + (size_t)(c0 + cc) * 256 + lane;
      float4 k0 = kr[0], k1 = kr[64], k2 = kr[128], k3 = kr[192];
      float qf[4] = { (&qv[0].x)[cc], (&qv[1].x)[cc], (&qv[2].x)[cc], (&qv[3].x)[cc] };
#pragma unroll
      for (int r = 0; r < 4; ++r) {
        float q = qf[r];
        acc[r][0].x += q * k0.x; acc[r][0].y += q * k0.y; acc[r][0].z += q * k0.z; acc[r][0].w += q * k0.w;
        acc[r][1].x += q * k1.x; acc[r][1].y += q * k1.y; acc[r][1].z += q * k1.z; acc[r][1].w += q * k1.w;
        acc[r][2].x += q * k2.x; acc[r][2].y += q * k2.y; acc[r][2].z += q * k2.z; acc[r][2].w += q * k2.w;
        acc[r][3].x += q * k3.x; acc[r][3].y += q * k3.y; acc[r][3].z += q * k3.z; acc[r][3].w += q * k3.w;
      }
    }
  }

  // ---- pack to sortable u32: hi 22 = score (sign-flip trick), lo 10 = 1023-idx (unique) ----
  unsigned pk[4][16];
#pragma unroll
  for (int r = 0; r < 4; ++r) {
#pragma unroll
    for (int j = 0; j < 4; ++j) {
      const float* av = &acc[r][j].x;
#pragma unroll
      for (int s = 0; s < 4; ++s) {
        unsigned u = __float_as_uint(av[s]);
        u ^= (unsigned)((int)u >> 31) | 0x80000000u;
        int idx = 256 * j + 4 * lane + s;
        pk[r][4 * j + s] = (u & 0xFFFFFC00u) | (unsigned)(1023 - idx);
      }
    }
  }

  // ---- ballot-quickselect: per-row exactly-40 threshold via bit descent ----
  unsigned p[4] = {0u, 0u, 0u, 0u};
  unsigned thr[4];
  bool done[4] = {false, false, false, false};
#pragma unroll 1
  for (int bit = 31; bit >= 0; --bit) {
#pragma unroll
    for (int r = 0; r < 4; ++r) {
      if (done[r]) continue;                       // wave-uniform branch
      unsigned X = p[r] | (1u << bit);
      int c = 0;
#pragma unroll
      for (int j = 0; j < 16; ++j)
        c += __popcll(__ballot(pk[r][j] >= X));
      if (c >= TOPK) p[r] = X;
      if (c == TOPK) { thr[r] = X; done[r] = true; }
    }
    if (done[0] && done[1] && done[2] && done[3]) break;
  }
#pragma unroll
  for (int r = 0; r < 4; ++r)
    if (!done[r]) thr[r] = p[r];                   // invariant: count(v>=p) == 40 after full descent

  // ---- emit: ballot + mbcnt rank -> scatter (arbitrary order within the set) ----
#pragma unroll
  for (int r = 0; r < 4; ++r) {
    const unsigned X = thr[r];
    int* srow = sel + ((size_t)(b * NR + r0 + row0 + r)) * TOPK;
    int base = 0;
#pragma unroll
    for (int j = 0; j < 16; ++j) {
      bool win = pk[r][j] >= X;
      unsigned long long m = __ballot(win);
      int before = __builtin_amdgcn_mbcnt_hi((unsigned)(m >> 32),
                   __builtin_amdgcn_mbcnt_lo((unsigned)m, 0));
      if (win) srow[base + before] = 1023 - (int)(pk[r][j] & 1023u);
      base += __popcll(m);
    }
  }
}

// ---------------------------------------------------------------- kernel 3: gathered attention + lepe depthwise + bias
// v2: + XCD-locality swizzle (grid 1D 16384; each XCD owns 2 batches -> gathered K/V working
// set ~2 MB fits per-XCD L2).
__global__ __launch_bounds__(256) void k_attn(
    const float* __restrict__ q_t, const float* __restrict__ k_t, const float* __restrict__ v_t,
    const int* __restrict__ sel, const float* __restrict__ lepe_w, const float* __restrict__ lepe_b,
    float* __restrict__ o_t)
{
  const int ib = blockIdx.x;
  const int xcd = ib & 7;
  const int slot = ib >> 3;               // 0..2047
  const int b = xcd * 2 + (slot >> 10);   // 2 batches per XCD
  const int r = slot & 1023;
  const int tid = threadIdx.x;

  __shared__ __align__(16) float kg[80][68];   // gathered K, 21.76 KB, rows 16B-aligned
  __shared__ __align__(16) float qb[2][64];
  __shared__ int   toff[80];                   // byte offset of gathered row within (b) plane
  __shared__ __align__(16) float lg[4][2][84]; // probs per head
  __shared__ float vl[4][64];                  // v rows 2r-1..2r+2 for lepe

  // part[half][sq][c] aliases kg (dead after QK^T)
  float (*part)[2][64] = (float (*)[2][64])&kg[0][0];

  if (tid < 40) {
    int s = sel[((size_t)(b * NR + r)) * TOPK + tid];
    toff[2 * tid]     = s * 512;        // row 2s   * 64 floats * 4 B
    toff[2 * tid + 1] = s * 512 + 256;  // row 2s+1
  }
  if (tid >= 128 && tid < 256) {
    int i = tid - 128;
    int s = i >> 6, c = i & 63;
    qb[s][c] = q_t[((size_t)(b * T + r * 2 + s)) * 64 + c];
  }
  {
    int idx = tid >> 6, c = tid & 63;
    int t = 2 * r - 1 + idx;
    vl[idx][c] = (t >= 0 && t < T) ? v_t[((size_t)(b * T + t)) * 64 + c] : 0.f;
  }
  __syncthreads();

  // ---- stage gathered K with float4 (5 iters/thread) ----
  {
    const char* kbase = (const char*)(k_t + (size_t)b * T * 64);
    for (int i = tid; i < 80 * 16; i += 256) {
      int row = i >> 4, c4 = i & 15;
      float4 kv = *(const float4*)(kbase + toff[row] + c4 * 16);
      *(float4*)&kg[row][c4 * 4] = kv;
    }
  }
  __syncthreads();

  const int h = tid >> 6, lane = tid & 63;

  // ---- QK^T: Q in registers, each gathered K row read once as 4 x b128, both sq per col ----
  {
    float4 q0[4], q1[4];
#pragma unroll
    for (int j = 0; j < 4; ++j) {
      q0[j] = *(const float4*)&qb[0][h * 16 + j * 4];
      q1[j] = *(const float4*)&qb[1][h * 16 + j * 4];
    }
    for (int col = lane; col < 80; col += 64) {
      float a0 = 0.f, a1 = 0.f;
#pragma unroll
      for (int j = 0; j < 4; ++j) {
        float4 kv = *(const float4*)&kg[col][h * 16 + j * 4];
        a0 += q0[j].x * kv.x + q0[j].y * kv.y + q0[j].z * kv.z + q0[j].w * kv.w;
        a1 += q1[j].x * kv.x + q1[j].y * kv.y + q1[j].z * kv.z + q1[j].w * kv.w;
      }
      lg[h][0][col] = a0 * 0.125f;  // 64^-0.5
      lg[h][1][col] = a1 * 0.125f;
    }
  }

  // ---- softmax (wave-local: lg[h] written and read by wave h only) ----
  for (int sq = 0; sq < 2; ++sq) {
    float a = lg[h][sq][lane];
    float bb = (lane < 16) ? lg[h][sq][64 + lane] : -INFINITY;
    float m = fmaxf(a, bb);
    for (int mm = 32; mm >= 1; mm >>= 1) m = fmaxf(m, __shfl_xor(m, mm));
    float ea = expf(a - m);
    float eb = (lane < 16) ? expf(bb - m) : 0.f;
    float ssum = ea + eb;
    for (int mm = 32; mm >= 1; mm >>= 1) ssum += __shfl_xor(ssum, mm);
    float inv = 1.f / ssum;
    lg[h][sq][lane] = ea * inv;
    if (lane < 16) lg[h][sq][64 + lane] = eb * inv;
  }
  __syncthreads();   // lg complete across heads; kg now dead -> part may reuse it

  // ---- PV: thread = (half, sq, c); p as float4, V rows coalesced from global (L2-hit) ----
  {
    const int c = tid & 63, j = tid >> 6;
    const int sq = j & 1, half = j >> 1;
    const int hh = c >> 4;
    const char* vbase = (const char*)(v_t + (size_t)b * T * 64) + c * 4;
    float acc = 0.f;
#pragma unroll 2
    for (int ch = 0; ch < 10; ++ch) {
      int col0 = half * 40 + ch * 4;
      float4 p = *(const float4*)&lg[hh][sq][col0];
      float v0 = *(const float*)(vbase + toff[col0 + 0]);
      float v1 = *(const float*)(vbase + toff[col0 + 1]);
      float v2 = *(const float*)(vbase + toff[col0 + 2]);
      float v3 = *(const float*)(vbase + toff[col0 + 3]);
      acc += p.x * v0 + p.y * v1 + p.z * v2 + p.w * v3;
    }
    part[half][sq][c] = acc;
  }
  __syncthreads();

  if (tid < 128) {
    int sq = tid >> 6, c = tid & 63;
    float o = part[0][sq][c] + part[1][sq][c];
    float lep = lepe_b[c];
#pragma unroll
    for (int kk = 0; kk < 3; ++kk) lep += lepe_w[c * 3 + kk] * vl[sq + kk][c];
    o_t[((size_t)(b * T + 2 * r + sq)) * 64 + c] = o + lep;
  }
}

// ---------------------------------------------------------------- kernel 4: out conv + residual + bn2 + fc1 + relu -> h_c (c-major)
__global__ __launch_bounds__(256) void k_mix(
    const float* __restrict__ x, const float* __restrict__ o_t,
    const float* __restrict__ out_w, const float* __restrict__ out_b,
    const float* __restrict__ n2_g, const float* __restrict__ n2_b,
    const float* __restrict__ fc1_w, const float* __restrict__ bn1_g, const float* __restrict__ bn1_b,
    float* __restrict__ xres, float* __restrict__ h_c)
{
  const int b = blockIdx.y;
  const int t0 = blockIdx.x * 16;
  const int tid = threadIdx.x;
  const float INVS = bnscale();

  __shared__ float ol[16][65];
  __shared__ float yn[16][65];
  __shared__ float xl[16][65];
  __shared__ float wo[64][65];    // out_w transposed: wo[cc][c]
  __shared__ float w1[128][65];   // fc1_w natural [cc][c]
  __shared__ float res2[128][17];

  for (int i = tid; i < 1024; i += 256) {
    int tt = i >> 6, c = i & 63;
    ol[tt][c] = o_t[((size_t)(b * T + t0 + tt)) * 64 + c];
  }
  for (int i = tid; i < 1024; i += 256) {
    int c = i >> 4, tt = i & 15;
    xl[tt][c] = x[(size_t)(b * 64 + c) * T + t0 + tt];
  }
  for (int i = tid; i < 4096; i += 256) {
    int c = i >> 6, cc = i & 63;
    wo[cc][c] = out_w[i];
  }
  for (int i = tid; i < 8192; i += 256) {
    int cc = i >> 6, c = i & 63;
    w1[cc][c] = fc1_w[i];
  }
  __syncthreads();

  // out conv: thread = (c, 4 tt's)
  {
    const int c = tid & 63, grp = tid >> 6;
    float a0 = out_b[c], a1 = a0, a2 = a0, a3 = a0;
    for (int cc = 0; cc < 64; ++cc) {
      float wv = wo[cc][c];
      a0 += wv * ol[grp * 4 + 0][cc];
      a1 += wv * ol[grp * 4 + 1][cc];
      a2 += wv * ol[grp * 4 + 2][cc];
      a3 += wv * ol[grp * 4 + 3][cc];
    }
    float g2 = n2_g[c] * INVS, b2 = n2_b[c];
    float av[4] = {a0, a1, a2, a3};
#pragma unroll
    for (int j = 0; j < 4; ++j) {
      int tt = grp * 4 + j;
      float xr = xl[tt][c] + av[j];
      xres[((size_t)(b * T + t0 + tt)) * 64 + c] = xr;
      yn[tt][c] = xr * g2 + b2;
    }
  }
  __syncthreads();

  // fc1 + bn1 + relu: thread = (cc, 8 tt's)
  {
    const int cc = tid & 127, half = tid >> 7;
    float acc[8];
#pragma unroll
    for (int j = 0; j < 8; ++j) acc[j] = 0.f;
    for (int c = 0; c < 64; ++c) {
      float wv = w1[cc][c];
#pragma unroll
      for (int j = 0; j < 8; ++j) acc[j] += wv * yn[half * 8 + j][c];
    }
    float g1 = bn1_g[cc] * INVS, b1 = bn1_b[cc];
#pragma unroll
    for (int j = 0; j < 8; ++j)
      res2[cc][half * 8 + j] = fmaxf(acc[j] * g1 + b1, 0.f);
  }
  __syncthreads();

  for (int i = tid; i < 2048; i += 256) {
    int tt = i & 15, cc = i >> 4;
    h_c[((size_t)(b * 128 + cc)) * T + t0 + tt] = res2[cc][tt];
  }
}

// ---------------------------------------------------------------- kernel 5: FFT radix-4 (5 stages + radix-2) -> diag filter + relu -> mirrored inverse
__global__ __launch_bounds__(256) void k_fft(
    const float* __restrict__ h_c, const float* __restrict__ fr, const float* __restrict__ fi,
    const float* __restrict__ frb, const float* __restrict__ fib, float* __restrict__ g_c)
{
  const int b = blockIdx.y;
  const int c2 = blockIdx.x;
  const int tid = threadIdx.x;

  __shared__ float re[2048];
  __shared__ float im[2048];
  __shared__ float twr[512];
  __shared__ float twi[512];

  for (int i = tid; i < 512; i += 256) {
    float ang = -6.283185307179586f * (float)i * (1.0f / 2048.0f);
    float sn, cs;
    sincosf(ang, &sn, &cs);
    twr[i] = cs; twi[i] = sn;
  }
  const float* hrow = h_c + ((size_t)(b * 128 + c2)) * T;
  for (int t = tid; t < 2048; t += 256) {
    re[t] = hrow[t];
    im[t] = 0.f;
  }
  __syncthreads();

  // ---- forward: 5 radix-4 DIF stages (span 2048..8) ----
#pragma unroll
  for (int m = 2048; m >= 8; m >>= 2) {
    const int q = m >> 2;
    const int f = 2048 / m;
#pragma unroll
    for (int k = tid; k < 512; k += 256) {
      int p = k & (q - 1);
      int g = k / q;
      int i0 = g * m + p, i1 = i0 + q, i2 = i0 + 2 * q, i3 = i0 + 3 * q;
      float a0r = re[i0], a0i = im[i0], a1r = re[i1], a1i = im[i1];
      float a2r = re[i2], a2i = im[i2], a3r = re[i3], a3i = im[i3];
      float s0r = a0r + a2r, s0i = a0i + a2i;
      float s1r = a0r - a2r, s1i = a0i - a2i;
      float s2r = a1r + a3r, s2i = a1i + a3i;
      float s3r = a1r - a3r, s3i = a1i - a3i;
      re[i0] = s0r + s2r; im[i0] = s0i + s2i;           // y0 = s0+s2
      float y1r = s1r + s3i, y1i = s1i - s3r;           // s1 - j*s3
      float y2r = s0r - s2r, y2i = s0i - s2i;           // s0 - s2
      float y3r = s1r - s3i, y3i = s1i + s3r;           // s1 + j*s3
      float w1r = twr[f * p], w1i = twi[f * p];
      float w2r = w1r * w1r - w1i * w1i, w2i = 2.f * w1r * w1i;
      float w3r = w2r * w1r - w2i * w1i, w3i = w2r * w1i + w2i * w1r;
      re[i1] = y1r * w1r - y1i * w1i; im[i1] = y1r * w1i + y1i * w1r;
      re[i2] = y2r * w2r - y2i * w2i; im[i2] = y2r * w2i + y2i * w2r;
      re[i3] = y3r * w3r - y3i * w3i; im[i3] = y3r * w3i + y3i * w3r;
    }
    __syncthreads();
  }
  // ---- final radix-2 stage (span 2, w = 1) ----
  for (int k = tid; k < 1024; k += 256) {
    int i0 = 2 * k, i1 = 2 * k + 1;
    float ur = re[i0], ui = im[i0], vr = re[i1], vi = im[i1];
    re[i0] = ur + vr; im[i0] = ui + vi;
    re[i1] = ur - vr; im[i1] = ui - vi;
  }
  __syncthreads();

  // ---- elementwise spectral filter (order-independent) ----
  const float SC = 0.022097086912079608f; // 1/sqrt(2048)
  const float fa = fr[c2 * 129];
  const float fb = fi[c2 * 129];
  const float fra = frb[c2];
  const float fia = fib[c2];
  for (int t = tid; t < 2048; t += 256) {
    float rr = re[t] * SC, ii = im[t] * SC;
    re[t] = fmaxf(rr * fa - ii * fb + fra, 0.f);
    im[t] = fmaxf(ii * fa + rr * fb + fia, 0.f);
  }
  __syncthreads();

  // ---- inverse: mirrored radix-2, then radix-4 spans 8..2048 with conj twiddles ----
  for (int k = tid; k < 1024; k += 256) {
    int i0 = 2 * k, i1 = 2 * k + 1;
    float ur = re[i0], ui = im[i0], vr = re[i1], vi = im[i1];
    re[i0] = ur + vr; im[i0] = ui + vi;
    re[i1] = ur - vr; im[i1] = ui - vi;
  }
  __syncthreads();
#pragma unroll
  for (int m = 8; m <= 2048; m <<= 2) {
    const int q = m >> 2;
    const int f = 2048 / m;
#pragma unroll
    for (int k = tid; k < 512; k += 256) {
      int p = k & (q - 1);
      int g = k / q;
      int i0 = g * m + p, i1 = i0 + q, i2 = i0 + 2 * q, i3 = i0 + 3 * q;
      float y0r = re[i0], y0i = im[i0];
      float b1r = re[i1], b1i = im[i1];
      float b2r = re[i2], b2i = im[i2];
      float b3r = re[i3], b3i = im[i3];
      float w1r = twr[f * p], w1i = twi[f * p];
      float w2r = w1r * w1r - w1i * w1i, w2i = 2.f * w1r * w1i;
      float w3r = w2r * w1r - w2i * w1i, w3i = w2r * w1i + w2i * w1r;
      // z = b * conj(w)
      float z1r = b1r * w1r + b1i * w1i, z1i = b1i * w1r - b1r * w1i;
      float z2r = b2r * w2r + b2i * w2i, z2i = b2i * w2r - b2r * w2i;
      float z3r = b3r * w3r + b3i * w3i, z3i = b3i * w3r - b3r * w3i;
      float u0r = y0r + z2r, u0i = y0i + z2i;   // 2*s0
      float u2r = y0r - z2r, u2i = y0i - z2i;   // 2*s2
      float u1r = z1r + z3r, u1i = z1i + z3i;   // 2*s1
      float dr = z1r - z3r, di = z1i - z3i;     // -2j*s3
      float u3r = -di, u3i = dr;                // 2*s3 = j*(z1-z3)
      re[i0] = u0r + u1r; im[i0] = u0i + u1i;   // 4*a0
      re[i2] = u0r - u1r; im[i2] = u0i - u1i;   // 4*a2
      re[i1] = u2r + u3r; im[i1] = u2i + u3i;   // 4*a1
      re[i3] = u2r - u3r; im[i3] = u2i - u3i;   // 4*a3
    }
    __syncthreads();
  }

  float* grow = g_c + ((size_t)(b * 128 + c2)) * T;
  for (int t = tid; t < 2048; t += 256)
    grow[t] = re[t] * SC;
}

// ---------------------------------------------------------------- kernel 6: fc2 + bn + final residual -> d_out (B,64,T)
__global__ __launch_bounds__(256) void k_out(
    const float* __restrict__ g_c, const float* __restrict__ xres,
    const float* __restrict__ fc2_w, const float* __restrict__ bn2_g, const float* __restrict__ bn2_b,
    float* __restrict__ out)
{
  const int b = blockIdx.y;
  const int t0 = blockIdx.x * 16;
  const int tid = threadIdx.x;
  const float INVS = bnscale();

  __shared__ float gl[16][129];
  __shared__ float w2[128][65];   // fc2_w transposed: w2[cc][c]
  __shared__ float res[64][17];

  for (int i = tid; i < 2048; i += 256) {
    int tt = i & 15, cc = i >> 4;
    gl[tt][cc] = g_c[((size_t)(b * 128 + cc)) * T + t0 + tt];
  }
  for (int i = tid; i < 8192; i += 256) {
    int c = i >> 7, cc = i & 127;
    w2[cc][c] = fc2_w[i];
  }
  __syncthreads();

  {
    const int c = tid & 63, grp = tid >> 6;
    float a0 = 0.f, a1 = 0.f, a2 = 0.f, a3 = 0.f;
    for (int cc = 0; cc < 128; ++cc) {
      float wv = w2[cc][c];
      a0 += wv * gl[grp * 4 + 0][cc];
      a1 += wv * gl[grp * 4 + 1][cc];
      a2 += wv * gl[grp * 4 + 2][cc];
      a3 += wv * gl[grp * 4 + 3][cc];
    }
    float g2 = bn2_g[c] * INVS, b2 = bn2_b[c];
    float av[4] = {a0, a1, a2, a3};
#pragma unroll
    for (int j = 0; j < 4; ++j) {
      int tt = grp * 4 + j;
      res[c][tt] = xres[((size_t)(b * T + t0 + tt)) * 64 + c] + av[j] * g2 + b2;
    }
  }
  __syncthreads();

  for (int i = tid; i < 1024; i += 256) {
    int tt = i & 15, c = i >> 4;
    out[(size_t)(b * 64 + c) * T + t0 + tt] = res[c][tt];
  }
}

// ----------------------------------------------------------------
extern "C" void kernel_launch(void* const* d_in, const int* in_sizes, int n_in,
                              void* d_out, int out_size, void* d_ws, size_t ws_size,
                              hipStream_t stream) {
  (void)in_sizes; (void)n_in; (void)out_size; (void)ws_size;
  const float* x     = (const float*)d_in[0];
  const float* n1_g  = (const float*)d_in[1];
  const float* n1_b  = (const float*)d_in[2];
  const float* wq    = (const float*)d_in[3];
  const float* bnq_g = (const float*)d_in[4];
  const float* bnq_b = (const float*)d_in[5];
  const float* wk    = (const float*)d_in[6];
  const float* bnk_g = (const float*)d_in[7];
  const float* bnk_b = (const float*)d_in[8];
  const float* wv    = (const float*)d_in[9];
  const float* lepe_w= (const float*)d_in[10];
  const float* lepe_b= (const float*)d_in[11];
  const float* out_w = (const float*)d_in[12];
  const float* out_b = (const float*)d_in[13];
  const float* n2_g  = (const float*)d_in[14];
  const float* n2_b  = (const float*)d_in[15];
  const float* fc1_w = (const float*)d_in[16];
  const float* bn1_g = (const float*)d_in[17];
  const float* bn1_b = (const float*)d_in[18];
  const float* fr    = (const float*)d_in[19];
  const float* fi    = (const float*)d_in[20];
  const float* frb   = (const float*)d_in[21];
  const float* fib   = (const float*)d_in[22];
  const float* fc2_w = (const float*)d_in[23];
  const float* bn2_g = (const float*)d_in[24];
  const float* bn2_b = (const float*)d_in[25];

  float* out = (float*)d_out;
  float* ws  = (float*)d_ws;
  const size_t M1 = (size_t)1 << 20;

  float* q_t  = ws;            // 2M floats
  float* k_t  = ws + 2 * M1;   // 2M
  float* v_t  = ws + 4 * M1;   // 2M
  float* q_rc = ws + 6 * M1;   // 1M  (c-major [b][c][r])
  float* k_rc = ws + 7 * M1;   // 1M
  float* o_t  = ws + 8 * M1;   // 2M
  float* xrs  = ws + 10 * M1;  // 2M
  int*   sel  = (int*)(ws + 12 * M1); // 0.64M ints
  float* h_c  = ws;            // 4M c-major [b][cc][t], reuses q_t+k_t (dead after k_attn)
  float* g_c  = ws + 4 * M1;   // 4M c-major, reuses v_t+q_rc+k_rc

  k_qkv<<<dim3(128, 16), 256, 0, stream>>>(x, n1_g, n1_b, wq, bnq_g, bnq_b,
                                           wk, bnk_g, bnk_b, wv, q_t, k_t, v_t, q_rc, k_rc);
  k_scores<<<dim3(512), 512, 0, stream>>>(q_rc, k_rc, sel);
  k_attn<<<dim3(16384), 256, 0, stream>>>(q_t, k_t, v_t, sel, lepe_w, lepe_b, o_t);
  k_mix<<<dim3(128, 16), 256, 0, stream>>>(x, o_t, out_w, out_b, n2_g, n2_b,
                                           fc1_w, bn1_g, bn1_b, xrs, h_c);
  k_fft<<<dim3(128, 16), 256, 0, stream>>>(h_c, fr, fi, frb, fib, g_c);
  k_out<<<dim3(128, 16), 256, 0, stream>>>(g_c, xrs, fc2_w, bn2_g, bn2_b, out);
}

// Round 15
// 409.798 us; speedup vs baseline: 1.0895x; 1.0173x over previous
//
#include <hip/hip_runtime.h>
#include <hip/hip_bf16.h>

#define T 2048
#define NR 1024
#define TOPK 40

static __device__ __forceinline__ float bnscale() { return 0.9999950000374997f; } // 1/sqrt(1+1e-5)

// ---------------------------------------------------------------- kernel 1: bn -> conv q,k (k=3) + v (k=1)
__global__ __launch_bounds__(256) void k_qkv(
    const float* __restrict__ x, const float* __restrict__ n1_g, const float* __restrict__ n1_b,
    const float* __restrict__ wq, const float* __restrict__ bnq_g, const float* __restrict__ bnq_b,
    const float* __restrict__ wk, const float* __restrict__ bnk_g, const float* __restrict__ bnk_b,
    const float* __restrict__ wv,
    float* __restrict__ q_t, float* __restrict__ k_t, float* __restrict__ v_t,
    float* __restrict__ q_rc, float* __restrict__ k_rc)
{
  const int b = blockIdx.y;
  const int tile = blockIdx.x >> 2;
  const int oc0 = (blockIdx.x & 3) * 16;
  const int t0 = tile * 64;
  const int r0 = tile * 32;
  const int tid = threadIdx.x;
  const float INVS = bnscale();

  __shared__ float xn[64][67];   // [c][tt], tt covers t0-1 .. t0+64
  __shared__ float ot[16][67];   // [oc_local][t_local]

  for (int i = tid; i < 64 * 66; i += 256) {
    int c = i / 66, tt = i - c * 66;
    int t = t0 + tt - 1;
    float v = (t >= 0 && t < T) ? x[(size_t)(b * 64 + c) * T + t] : 0.f;
    xn[c][tt] = v * (n1_g[c] * INVS) + n1_b[c];
  }
  __syncthreads();

  const int w = tid >> 6, lane = tid & 63;
  const int ob = oc0 + __builtin_amdgcn_readfirstlane(w) * 4;  // wave-uniform -> SGPR weight loads

  float accq[4], acck[4], accv[4];
#pragma unroll
  for (int j = 0; j < 4; ++j) { accq[j] = 0.f; acck[j] = 0.f; accv[j] = 0.f; }

#pragma unroll 1
  for (int c0 = 0; c0 < 64; c0 += 4) {
    float xr[4][3];
#pragma unroll
    for (int cc = 0; cc < 4; ++cc) {
      xr[cc][0] = xn[c0 + cc][lane];
      xr[cc][1] = xn[c0 + cc][lane + 1];
      xr[cc][2] = xn[c0 + cc][lane + 2];
    }
#pragma unroll
    for (int o4 = 0; o4 < 4; ++o4) {
      int o = ob + o4;
      const float* wqo = wq + o * 192 + c0 * 3;
      const float* wko = wk + o * 192 + c0 * 3;
      const float* wvo = wv + o * 64 + c0;
      float aq = accq[o4], ak = acck[o4], av = accv[o4];
#pragma unroll
      for (int cc = 0; cc < 4; ++cc) {
        aq += xr[cc][0] * wqo[cc * 3 + 0] + xr[cc][1] * wqo[cc * 3 + 1] + xr[cc][2] * wqo[cc * 3 + 2];
        ak += xr[cc][0] * wko[cc * 3 + 0] + xr[cc][1] * wko[cc * 3 + 1] + xr[cc][2] * wko[cc * 3 + 2];
        av += xr[cc][1] * wvo[cc];
      }
      accq[o4] = aq; acck[o4] = ak; accv[o4] = av;
    }
  }

  // ---- Q: bn, transpose-store slice, region means ----
#pragma unroll
  for (int o4 = 0; o4 < 4; ++o4) {
    int o = ob + o4;
    ot[o - oc0][lane] = accq[o4] * (bnq_g[o] * INVS) + bnq_b[o];
  }
  __syncthreads();
  for (int i = tid; i < 1024; i += 256) {
    int cl = i & 15, tt = i >> 4;
    q_t[((size_t)(b * T + t0 + tt)) * 64 + oc0 + cl] = ot[cl][tt];
  }
  for (int i = tid; i < 512; i += 256) {
    int rr = i & 31, cl = i >> 5;
    q_rc[((size_t)(b * 64 + oc0 + cl)) * NR + r0 + rr] = 0.5f * (ot[cl][2 * rr] + ot[cl][2 * rr + 1]);
  }
  __syncthreads();

  // ---- K ----
#pragma unroll
  for (int o4 = 0; o4 < 4; ++o4) {
    int o = ob + o4;
    ot[o - oc0][lane] = acck[o4] * (bnk_g[o] * INVS) + bnk_b[o];
  }
  __syncthreads();
  for (int i = tid; i < 1024; i += 256) {
    int cl = i & 15, tt = i >> 4;
    k_t[((size_t)(b * T + t0 + tt)) * 64 + oc0 + cl] = ot[cl][tt];
  }
  for (int i = tid; i < 512; i += 256) {
    int rr = i & 31, cl = i >> 5;
    k_rc[((size_t)(b * 64 + oc0 + cl)) * NR + r0 + rr] = 0.5f * (ot[cl][2 * rr] + ot[cl][2 * rr + 1]);
  }
  __syncthreads();

  // ---- V ----
#pragma unroll
  for (int o4 = 0; o4 < 4; ++o4) {
    ot[ob + o4 - oc0][lane] = accv[o4];
  }
  __syncthreads();
  for (int i = tid; i < 1024; i += 256) {
    int cl = i & 15, tt = i >> 4;
    v_t[((size_t)(b * T + t0 + tt)) * 64 + oc0 + cl] = ot[cl][tt];
  }
}

// ---------------------------------------------------------------- kernel 2: region scores + top-40
// v11: v6 structure (4 waves/block, full 1024 cols/wave, ballot-quickselect, unroll 1) at
// 8 rows/block / 2 rows/wave: grid 2048 -> 8 blocks/CU -> 8 waves/SIMD (2x v6). All pipes sat
// at ~1/3 concurrently (VALU 34%, L1 35%, L2 34%) = dependency-limited round-robin; doubling
// resident waves halves the exposed wait. Aggregate select work occupancy-invariant
// (quickselect, unlike v2's serial extraction which sank the old 8-row split). Aggregate B
// traffic doubles to ~68% of L2 ceiling -- headroom. XCD swizzle: 256 slots/XCD = 2b x 128t.
__global__ __launch_bounds__(256) void k_scores(
    const float* __restrict__ q_rc, const float* __restrict__ k_rc, int* __restrict__ sel)
{
  const int ib = blockIdx.x;
  const int xcd = ib & 7;
  const int slot = ib >> 3;             // 0..255
  const int b = xcd * 2 + (slot >> 7);  // 2 batches per XCD
  const int r0 = (slot & 127) * 8;      // 8 rows per block
  const int tid = threadIdx.x;
  const int w = tid >> 6, lane = tid & 63;

  __shared__ float qsT[8][68];    // [row][c], pad 68 keeps float4 alignment

  for (int i = tid; i < 512; i += 256) {
    int rr = i & 7, c = i >> 3;
    qsT[rr][c] = q_rc[((size_t)(b * 64 + c)) * NR + r0 + rr];
  }
  __syncthreads();

  const int row0 = w * 2;

  // ---- GEMM: wave computes rows r0+row0..+1; lane holds cols {256j + 4lane + s}
  float4 acc[2][4];
#pragma unroll
  for (int r = 0; r < 2; ++r)
#pragma unroll
    for (int j = 0; j < 4; ++j) acc[r][j] = make_float4(0.f, 0.f, 0.f, 0.f);

  const float4* kp = (const float4*)(k_rc + ((size_t)b * 64) * NR);
#pragma unroll 1
  for (int c0 = 0; c0 < 64; c0 += 4) {
    float4 qv[2];
    qv[0] = *(const float4*)&qsT[row0 + 0][c0];
    qv[1] = *(const float4*)&qsT[row0 + 1][c0];
#pragma unroll
    for (int cc = 0; cc < 4; ++cc) {
      const float4* kr = kp + (size_t)(c0 + cc) * 256 + lane;
      float4 k0 = kr[0], k1 = kr[64], k2 = kr[128], k3 = kr[192];
      float q0 = (&qv[0].x)[cc], q1 = (&qv[1].x)[cc];
      acc[0][0].x += q0 * k0.x; acc[0][0].y += q0 * k0.y; acc[0][0].z += q0 * k0.z; acc[0][0].w += q0 * k0.w;
      acc[0][1].x += q0 * k1.x; acc[0][1].y += q0 * k1.y; acc[0][1].z += q0 * k1.z; acc[0][1].w += q0 * k1.w;
      acc[0][2].x += q0 * k2.x; acc[0][2].y += q0 * k2.y; acc[0][2].z += q0 * k2.z; acc[0][2].w += q0 * k2.w;
      acc[0][3].x += q0 * k3.x; acc[0][3].y += q0 * k3.y; acc[0][3].z += q0 * k3.z; acc[0][3].w += q0 * k3.w;
      acc[1][0].x += q1 * k0.x; acc[1][0].y += q1 * k0.y; acc[1][0].z += q1 * k0.z; acc[1][0].w += q1 * k0.w;
      acc[1][1].x += q1 * k1.x; acc[1][1].y += q1 * k1.y; acc[1][1].z += q1 * k1.z; acc[1][1].w += q1 * k1.w;
      acc[1][2].x += q1 * k2.x; acc[1][2].y += q1 * k2.y; acc[1][2].z += q1 * k2.z; acc[1][2].w += q1 * k2.w;
      acc[1][3].x += q1 * k3.x; acc[1][3].y += q1 * k3.y; acc[1][3].z += q1 * k3.z; acc[1][3].w += q1 * k3.w;
    }
  }

  // ---- pack to sortable u32: hi 22 = score (sign-flip trick), lo 10 = 1023-idx (unique) ----
  unsigned pk[2][16];
#pragma unroll
  for (int r = 0; r < 2; ++r) {
#pragma unroll
    for (int j = 0; j < 4; ++j) {
      const float* av = &acc[r][j].x;
#pragma unroll
      for (int s = 0; s < 4; ++s) {
        unsigned u = __float_as_uint(av[s]);
        u ^= (unsigned)((int)u >> 31) | 0x80000000u;
        int idx = 256 * j + 4 * lane + s;
        pk[r][4 * j + s] = (u & 0xFFFFFC00u) | (unsigned)(1023 - idx);
      }
    }
  }

  // ---- ballot-quickselect: per-row exactly-40 threshold via bit descent ----
  unsigned p[2] = {0u, 0u};
  unsigned thr[2];
  bool done[2] = {false, false};
#pragma unroll 1
  for (int bit = 31; bit >= 0; --bit) {
#pragma unroll
    for (int r = 0; r < 2; ++r) {
      if (done[r]) continue;                       // wave-uniform branch
      unsigned X = p[r] | (1u << bit);
      int c = 0;
#pragma unroll
      for (int j = 0; j < 16; ++j)
        c += __popcll(__ballot(pk[r][j] >= X));
      if (c >= TOPK) p[r] = X;
      if (c == TOPK) { thr[r] = X; done[r] = true; }
    }
    if (done[0] && done[1]) break;
  }
#pragma unroll
  for (int r = 0; r < 2; ++r)
    if (!done[r]) thr[r] = p[r];                   // invariant: count(v>=p) == 40 after full descent

  // ---- emit: ballot + mbcnt rank -> scatter (arbitrary order within the set) ----
#pragma unroll
  for (int r = 0; r < 2; ++r) {
    const unsigned X = thr[r];
    int* srow = sel + ((size_t)(b * NR + r0 + row0 + r)) * TOPK;
    int base = 0;
#pragma unroll
    for (int j = 0; j < 16; ++j) {
      bool win = pk[r][j] >= X;
      unsigned long long m = __ballot(win);
      int before = __builtin_amdgcn_mbcnt_hi((unsigned)(m >> 32),
                   __builtin_amdgcn_mbcnt_lo((unsigned)m, 0));
      if (win) srow[base + before] = 1023 - (int)(pk[r][j] & 1023u);
      base += __popcll(m);
    }
  }
}

// ---------------------------------------------------------------- kernel 3: gathered attention + lepe depthwise + bias
// v2: + XCD-locality swizzle (grid 1D 16384; each XCD owns 2 batches -> gathered K/V working
// set ~2 MB fits per-XCD L2).
__global__ __launch_bounds__(256) void k_attn(
    const float* __restrict__ q_t, const float* __restrict__ k_t, const float* __restrict__ v_t,
    const int* __restrict__ sel, const float* __restrict__ lepe_w, const float* __restrict__ lepe_b,
    float* __restrict__ o_t)
{
  const int ib = blockIdx.x;
  const int xcd = ib & 7;
  const int slot = ib >> 3;               // 0..2047
  const int b = xcd * 2 + (slot >> 10);   // 2 batches per XCD
  const int r = slot & 1023;
  const int tid = threadIdx.x;

  __shared__ __align__(16) float kg[80][68];   // gathered K, 21.76 KB, rows 16B-aligned
  __shared__ __align__(16) float qb[2][64];
  __shared__ int   toff[80];                   // byte offset of gathered row within (b) plane
  __shared__ __align__(16) float lg[4][2][84]; // probs per head
  __shared__ float vl[4][64];                  // v rows 2r-1..2r+2 for lepe

  // part[half][sq][c] aliases kg (dead after QK^T)
  float (*part)[2][64] = (float (*)[2][64])&kg[0][0];

  if (tid < 40) {
    int s = sel[((size_t)(b * NR + r)) * TOPK + tid];
    toff[2 * tid]     = s * 512;        // row 2s   * 64 floats * 4 B
    toff[2 * tid + 1] = s * 512 + 256;  // row 2s+1
  }
  if (tid >= 128 && tid < 256) {
    int i = tid - 128;
    int s = i >> 6, c = i & 63;
    qb[s][c] = q_t[((size_t)(b * T + r * 2 + s)) * 64 + c];
  }
  {
    int idx = tid >> 6, c = tid & 63;
    int t = 2 * r - 1 + idx;
    vl[idx][c] = (t >= 0 && t < T) ? v_t[((size_t)(b * T + t)) * 64 + c] : 0.f;
  }
  __syncthreads();

  // ---- stage gathered K with float4 (5 iters/thread) ----
  {
    const char* kbase = (const char*)(k_t + (size_t)b * T * 64);
    for (int i = tid; i < 80 * 16; i += 256) {
      int row = i >> 4, c4 = i & 15;
      float4 kv = *(const float4*)(kbase + toff[row] + c4 * 16);
      *(float4*)&kg[row][c4 * 4] = kv;
    }
  }
  __syncthreads();

  const int h = tid >> 6, lane = tid & 63;

  // ---- QK^T: Q in registers, each gathered K row read once as 4 x b128, both sq per col ----
  {
    float4 q0[4], q1[4];
#pragma unroll
    for (int j = 0; j < 4; ++j) {
      q0[j] = *(const float4*)&qb[0][h * 16 + j * 4];
      q1[j] = *(const float4*)&qb[1][h * 16 + j * 4];
    }
    for (int col = lane; col < 80; col += 64) {
      float a0 = 0.f, a1 = 0.f;
#pragma unroll
      for (int j = 0; j < 4; ++j) {
        float4 kv = *(const float4*)&kg[col][h * 16 + j * 4];
        a0 += q0[j].x * kv.x + q0[j].y * kv.y + q0[j].z * kv.z + q0[j].w * kv.w;
        a1 += q1[j].x * kv.x + q1[j].y * kv.y + q1[j].z * kv.z + q1[j].w * kv.w;
      }
      lg[h][0][col] = a0 * 0.125f;  // 64^-0.5
      lg[h][1][col] = a1 * 0.125f;
    }
  }

  // ---- softmax (wave-local: lg[h] written and read by wave h only) ----
  for (int sq = 0; sq < 2; ++sq) {
    float a = lg[h][sq][lane];
    float bb = (lane < 16) ? lg[h][sq][64 + lane] : -INFINITY;
    float m = fmaxf(a, bb);
    for (int mm = 32; mm >= 1; mm >>= 1) m = fmaxf(m, __shfl_xor(m, mm));
    float ea = expf(a - m);
    float eb = (lane < 16) ? expf(bb - m) : 0.f;
    float ssum = ea + eb;
    for (int mm = 32; mm >= 1; mm >>= 1) ssum += __shfl_xor(ssum, mm);
    float inv = 1.f / ssum;
    lg[h][sq][lane] = ea * inv;
    if (lane < 16) lg[h][sq][64 + lane] = eb * inv;
  }
  __syncthreads();   // lg complete across heads; kg now dead -> part may reuse it

  // ---- PV: thread = (half, sq, c); p as float4, V rows coalesced from global (L2-hit) ----
  {
    const int c = tid & 63, j = tid >> 6;
    const int sq = j & 1, half = j >> 1;
    const int hh = c >> 4;
    const char* vbase = (const char*)(v_t + (size_t)b * T * 64) + c * 4;
    float acc = 0.f;
#pragma unroll 2
    for (int ch = 0; ch < 10; ++ch) {
      int col0 = half * 40 + ch * 4;
      float4 p = *(const float4*)&lg[hh][sq][col0];
      float v0 = *(const float*)(vbase + toff[col0 + 0]);
      float v1 = *(const float*)(vbase + toff[col0 + 1]);
      float v2 = *(const float*)(vbase + toff[col0 + 2]);
      float v3 = *(const float*)(vbase + toff[col0 + 3]);
      acc += p.x * v0 + p.y * v1 + p.z * v2 + p.w * v3;
    }
    part[half][sq][c] = acc;
  }
  __syncthreads();

  if (tid < 128) {
    int sq = tid >> 6, c = tid & 63;
    float o = part[0][sq][c] + part[1][sq][c];
    float lep = lepe_b[c];
#pragma unroll
    for (int kk = 0; kk < 3; ++kk) lep += lepe_w[c * 3 + kk] * vl[sq + kk][c];
    o_t[((size_t)(b * T + 2 * r + sq)) * 64 + c] = o + lep;
  }
}

// ---------------------------------------------------------------- kernel 4: out conv + residual + bn2 + fc1 + relu -> h_c (c-major)
__global__ __launch_bounds__(256) void k_mix(
    const float* __restrict__ x, const float* __restrict__ o_t,
    const float* __restrict__ out_w, const float* __restrict__ out_b,
    const float* __restrict__ n2_g, const float* __restrict__ n2_b,
    const float* __restrict__ fc1_w, const float* __restrict__ bn1_g, const float* __restrict__ bn1_b,
    float* __restrict__ xres, float* __restrict__ h_c)
{
  const int b = blockIdx.y;
  const int t0 = blockIdx.x * 16;
  const int tid = threadIdx.x;
  const float INVS = bnscale();

  __shared__ float ol[16][65];
  __shared__ float yn[16][65];
  __shared__ float xl[16][65];
  __shared__ float wo[64][65];    // out_w transposed: wo[cc][c]
  __shared__ float w1[128][65];   // fc1_w natural [cc][c]
  __shared__ float res2[128][17];

  for (int i = tid; i < 1024; i += 256) {
    int tt = i >> 6, c = i & 63;
    ol[tt][c] = o_t[((size_t)(b * T + t0 + tt)) * 64 + c];
  }
  for (int i = tid; i < 1024; i += 256) {
    int c = i >> 4, tt = i & 15;
    xl[tt][c] = x[(size_t)(b * 64 + c) * T + t0 + tt];
  }
  for (int i = tid; i < 4096; i += 256) {
    int c = i >> 6, cc = i & 63;
    wo[cc][c] = out_w[i];
  }
  for (int i = tid; i < 8192; i += 256) {
    int cc = i >> 6, c = i & 63;
    w1[cc][c] = fc1_w[i];
  }
  __syncthreads();

  // out conv: thread = (c, 4 tt's)
  {
    const int c = tid & 63, grp = tid >> 6;
    float a0 = out_b[c], a1 = a0, a2 = a0, a3 = a0;
    for (int cc = 0; cc < 64; ++cc) {
      float wv = wo[cc][c];
      a0 += wv * ol[grp * 4 + 0][cc];
      a1 += wv * ol[grp * 4 + 1][cc];
      a2 += wv * ol[grp * 4 + 2][cc];
      a3 += wv * ol[grp * 4 + 3][cc];
    }
    float g2 = n2_g[c] * INVS, b2 = n2_b[c];
    float av[4] = {a0, a1, a2, a3};
#pragma unroll
    for (int j = 0; j < 4; ++j) {
      int tt = grp * 4 + j;
      float xr = xl[tt][c] + av[j];
      xres[((size_t)(b * T + t0 + tt)) * 64 + c] = xr;
      yn[tt][c] = xr * g2 + b2;
    }
  }
  __syncthreads();

  // fc1 + bn1 + relu: thread = (cc, 8 tt's)
  {
    const int cc = tid & 127, half = tid >> 7;
    float acc[8];
#pragma unroll
    for (int j = 0; j < 8; ++j) acc[j] = 0.f;
    for (int c = 0; c < 64; ++c) {
      float wv = w1[cc][c];
#pragma unroll
      for (int j = 0; j < 8; ++j) acc[j] += wv * yn[half * 8 + j][c];
    }
    float g1 = bn1_g[cc] * INVS, b1 = bn1_b[cc];
#pragma unroll
    for (int j = 0; j < 8; ++j)
      res2[cc][half * 8 + j] = fmaxf(acc[j] * g1 + b1, 0.f);
  }
  __syncthreads();

  for (int i = tid; i < 2048; i += 256) {
    int tt = i & 15, cc = i >> 4;
    h_c[((size_t)(b * 128 + cc)) * T + t0 + tt] = res2[cc][tt];
  }
}

// ---------------------------------------------------------------- kernel 5: FFT radix-4 (5 stages + radix-2) -> diag filter + relu -> mirrored inverse
__global__ __launch_bounds__(256) void k_fft(
    const float* __restrict__ h_c, const float* __restrict__ fr, const float* __restrict__ fi,
    const float* __restrict__ frb, const float* __restrict__ fib, float* __restrict__ g_c)
{
  const int b = blockIdx.y;
  const int c2 = blockIdx.x;
  const int tid = threadIdx.x;

  __shared__ float re[2048];
  __shared__ float im[2048];
  __shared__ float twr[512];
  __shared__ float twi[512];

  for (int i = tid; i < 512; i += 256) {
    float ang = -6.283185307179586f * (float)i * (1.0f / 2048.0f);
    float sn, cs;
    sincosf(ang, &sn, &cs);
    twr[i] = cs; twi[i] = sn;
  }
  const float* hrow = h_c + ((size_t)(b * 128 + c2)) * T;
  for (int t = tid; t < 2048; t += 256) {
    re[t] = hrow[t];
    im[t] = 0.f;
  }
  __syncthreads();

  // ---- forward: 5 radix-4 DIF stages (span 2048..8) ----
#pragma unroll
  for (int m = 2048; m >= 8; m >>= 2) {
    const int q = m >> 2;
    const int f = 2048 / m;
#pragma unroll
    for (int k = tid; k < 512; k += 256) {
      int p = k & (q - 1);
      int g = k / q;
      int i0 = g * m + p, i1 = i0 + q, i2 = i0 + 2 * q, i3 = i0 + 3 * q;
      float a0r = re[i0], a0i = im[i0], a1r = re[i1], a1i = im[i1];
      float a2r = re[i2], a2i = im[i2], a3r = re[i3], a3i = im[i3];
      float s0r = a0r + a2r, s0i = a0i + a2i;
      float s1r = a0r - a2r, s1i = a0i - a2i;
      float s2r = a1r + a3r, s2i = a1i + a3i;
      float s3r = a1r - a3r, s3i = a1i - a3i;
      re[i0] = s0r + s2r; im[i0] = s0i + s2i;           // y0 = s0+s2
      float y1r = s1r + s3i, y1i = s1i - s3r;           // s1 - j*s3
      float y2r = s0r - s2r, y2i = s0i - s2i;           // s0 - s2
      float y3r = s1r - s3i, y3i = s1i + s3r;           // s1 + j*s3
      float w1r = twr[f * p], w1i = twi[f * p];
      float w2r = w1r * w1r - w1i * w1i, w2i = 2.f * w1r * w1i;
      float w3r = w2r * w1r - w2i * w1i, w3i = w2r * w1i + w2i * w1r;
      re[i1] = y1r * w1r - y1i * w1i; im[i1] = y1r * w1i + y1i * w1r;
      re[i2] = y2r * w2r - y2i * w2i; im[i2] = y2r * w2i + y2i * w2r;
      re[i3] = y3r * w3r - y3i * w3i; im[i3] = y3r * w3i + y3i * w3r;
    }
    __syncthreads();
  }
  // ---- final radix-2 stage (span 2, w = 1) ----
  for (int k = tid; k < 1024; k += 256) {
    int i0 = 2 * k, i1 = 2 * k + 1;
    float ur = re[i0], ui = im[i0], vr = re[i1], vi = im[i1];
    re[i0] = ur + vr; im[i0] = ui + vi;
    re[i1] = ur - vr; im[i1] = ui - vi;
  }
  __syncthreads();

  // ---- elementwise spectral filter (order-independent) ----
  const float SC = 0.022097086912079608f; // 1/sqrt(2048)
  const float fa = fr[c2 * 129];
  const float fb = fi[c2 * 129];
  const float fra = frb[c2];
  const float fia = fib[c2];
  for (int t = tid; t < 2048; t += 256) {
    float rr = re[t] * SC, ii = im[t] * SC;
    re[t] = fmaxf(rr * fa - ii * fb + fra, 0.f);
    im[t] = fmaxf(ii * fa + rr * fb + fia, 0.f);
  }
  __syncthreads();

  // ---- inverse: mirrored radix-2, then radix-4 spans 8..2048 with conj twiddles ----
  for (int k = tid; k < 1024; k += 256) {
    int i0 = 2 * k, i1 = 2 * k + 1;
    float ur = re[i0], ui = im[i0], vr = re[i1], vi = im[i1];
    re[i0] = ur + vr; im[i0] = ui + vi;
    re[i1] = ur - vr; im[i1] = ui - vi;
  }
  __syncthreads();
#pragma unroll
  for (int m = 8; m <= 2048; m <<= 2) {
    const int q = m >> 2;
    const int f = 2048 / m;
#pragma unroll
    for (int k = tid; k < 512; k += 256) {
      int p = k & (q - 1);
      int g = k / q;
      int i0 = g * m + p, i1 = i0 + q, i2 = i0 + 2 * q, i3 = i0 + 3 * q;
      float y0r = re[i0], y0i = im[i0];
      float b1r = re[i1], b1i = im[i1];
      float b2r = re[i2], b2i = im[i2];
      float b3r = re[i3], b3i = im[i3];
      float w1r = twr[f * p], w1i = twi[f * p];
      float w2r = w1r * w1r - w1i * w1i, w2i = 2.f * w1r * w1i;
      float w3r = w2r * w1r - w2i * w1i, w3i = w2r * w1i + w2i * w1r;
      // z = b * conj(w)
      float z1r = b1r * w1r + b1i * w1i, z1i = b1i * w1r - b1r * w1i;
      float z2r = b2r * w2r + b2i * w2i, z2i = b2i * w2r - b2r * w2i;
      float z3r = b3r * w3r + b3i * w3i, z3i = b3i * w3r - b3r * w3i;
      float u0r = y0r + z2r, u0i = y0i + z2i;   // 2*s0
      float u2r = y0r - z2r, u2i = y0i - z2i;   // 2*s2
      float u1r = z1r + z3r, u1i = z1i + z3i;   // 2*s1
      float dr = z1r - z3r, di = z1i - z3i;     // -2j*s3
      float u3r = -di, u3i = dr;                // 2*s3 = j*(z1-z3)
      re[i0] = u0r + u1r; im[i0] = u0i + u1i;   // 4*a0
      re[i2] = u0r - u1r; im[i2] = u0i - u1i;   // 4*a2
      re[i1] = u2r + u3r; im[i1] = u2i + u3i;   // 4*a1
      re[i3] = u2r - u3r; im[i3] = u2i - u3i;   // 4*a3
    }
    __syncthreads();
  }

  float* grow = g_c + ((size_t)(b * 128 + c2)) * T;
  for (int t = tid; t < 2048; t += 256)
    grow[t] = re[t] * SC;
}

// ---------------------------------------------------------------- kernel 6: fc2 + bn + final residual -> d_out (B,64,T)
__global__ __launch_bounds__(256) void k_out(
    const float* __restrict__ g_c, const float* __restrict__ xres,
    const float* __restrict__ fc2_w, const float* __restrict__ bn2_g, const float* __restrict__ bn2_b,
    float* __restrict__ out)
{
  const int b = blockIdx.y;
  const int t0 = blockIdx.x * 16;
  const int tid = threadIdx.x;
  const float INVS = bnscale();

  __shared__ float gl[16][129];
  __shared__ float w2[128][65];   // fc2_w transposed: w2[cc][c]
  __shared__ float res[64][17];

  for (int i = tid; i < 2048; i += 256) {
    int tt = i & 15, cc = i >> 4;
    gl[tt][cc] = g_c[((size_t)(b * 128 + cc)) * T + t0 + tt];
  }
  for (int i = tid; i < 8192; i += 256) {
    int c = i >> 7, cc = i & 127;
    w2[cc][c] = fc2_w[i];
  }
  __syncthreads();

  {
    const int c = tid & 63, grp = tid >> 6;
    float a0 = 0.f, a1 = 0.f, a2 = 0.f, a3 = 0.f;
    for (int cc = 0; cc < 128; ++cc) {
      float wv = w2[cc][c];
      a0 += wv * gl[grp * 4 + 0][cc];
      a1 += wv * gl[grp * 4 + 1][cc];
      a2 += wv * gl[grp * 4 + 2][cc];
      a3 += wv * gl[grp * 4 + 3][cc];
    }
    float g2 = bn2_g[c] * INVS, b2 = bn2_b[c];
    float av[4] = {a0, a1, a2, a3};
#pragma unroll
    for (int j = 0; j < 4; ++j) {
      int tt = grp * 4 + j;
      res[c][tt] = xres[((size_t)(b * T + t0 + tt)) * 64 + c] + av[j] * g2 + b2;
    }
  }
  __syncthreads();

  for (int i = tid; i < 1024; i += 256) {
    int tt = i & 15, c = i >> 4;
    out[(size_t)(b * 64 + c) * T + t0 + tt] = res[c][tt];
  }
}

// ----------------------------------------------------------------
extern "C" void kernel_launch(void* const* d_in, const int* in_sizes, int n_in,
                              void* d_out, int out_size, void* d_ws, size_t ws_size,
                              hipStream_t stream) {
  (void)in_sizes; (void)n_in; (void)out_size; (void)ws_size;
  const float* x     = (const float*)d_in[0];
  const float* n1_g  = (const float*)d_in[1];
  const float* n1_b  = (const float*)d_in[2];
  const float* wq    = (const float*)d_in[3];
  const float* bnq_g = (const float*)d_in[4];
  const float* bnq_b = (const float*)d_in[5];
  const float* wk    = (const float*)d_in[6];
  const float* bnk_g = (const float*)d_in[7];
  const float* bnk_b = (const float*)d_in[8];
  const float* wv    = (const float*)d_in[9];
  const float* lepe_w= (const float*)d_in[10];
  const float* lepe_b= (const float*)d_in[11];
  const float* out_w = (const float*)d_in[12];
  const float* out_b = (const float*)d_in[13];
  const float* n2_g  = (const float*)d_in[14];
  const float* n2_b  = (const float*)d_in[15];
  const float* fc1_w = (const float*)d_in[16];
  const float* bn1_g = (const float*)d_in[17];
  const float* bn1_b = (const float*)d_in[18];
  const float* fr    = (const float*)d_in[19];
  const float* fi    = (const float*)d_in[20];
  const float* frb   = (const float*)d_in[21];
  const float* fib   = (const float*)d_in[22];
  const float* fc2_w = (const float*)d_in[23];
  const float* bn2_g = (const float*)d_in[24];
  const float* bn2_b = (const float*)d_in[25];

  float* out = (float*)d_out;
  float* ws  = (float*)d_ws;
  const size_t M1 = (size_t)1 << 20;

  float* q_t  = ws;            // 2M floats
  float* k_t  = ws + 2 * M1;   // 2M
  float* v_t  = ws + 4 * M1;   // 2M
  float* q_rc = ws + 6 * M1;   // 1M  (c-major [b][c][r])
  float* k_rc = ws + 7 * M1;   // 1M
  float* o_t  = ws + 8 * M1;   // 2M
  float* xrs  = ws + 10 * M1;  // 2M
  int*   sel  = (int*)(ws + 12 * M1); // 0.64M ints
  float* h_c  = ws;            // 4M c-major [b][cc][t], reuses q_t+k_t (dead after k_attn)
  float* g_c  = ws + 4 * M1;   // 4M c-major, reuses v_t+q_rc+k_rc

  k_qkv<<<dim3(128, 16), 256, 0, stream>>>(x, n1_g, n1_b, wq, bnq_g, bnq_b,
                                           wk, bnk_g, bnk_b, wv, q_t, k_t, v_t, q_rc, k_rc);
  k_scores<<<dim3(2048), 256, 0, stream>>>(q_rc, k_rc, sel);
  k_attn<<<dim3(16384), 256, 0, stream>>>(q_t, k_t, v_t, sel, lepe_w, lepe_b, o_t);
  k_mix<<<dim3(128, 16), 256, 0, stream>>>(x, o_t, out_w, out_b, n2_g, n2_b,
                                           fc1_w, bn1_g, bn1_b, xrs, h_c);
  k_fft<<<dim3(128, 16), 256, 0, stream>>>(h_c, fr, fi, frb, fib, g_c);
  k_out<<<dim3(128, 16), 256, 0, stream>>>(g_c, xrs, fc2_w, bn2_g, bn2_b, out);
}